// Round 1
// baseline (1124.977 us; speedup 1.0000x reference)
//
#include <hip/hip_runtime.h>

// ---------------------------------------------------------------------------
// TRTAttention: windowed ViT attention, L=2304 (=48*48), dim=768, 12 heads x 64
// Round 1: fp32 correctness-first baseline.
//   k1: rope tables  k2: qkv gemm  k3: split+rope  k4: rel bias  k5: flash attn
//   k6: proj gemm
// ---------------------------------------------------------------------------

namespace {
constexpr int LTOK = 2304;   // 48*48
constexpr int DIMC = 768;
constexpr int NH   = 12;
constexpr int HD   = 64;
constexpr int WG   = 48;
constexpr int QKVN = 2304;   // 3*768
constexpr float SCALE = 0.125f;  // 64^-0.5
}

// --------------------------- k1: rope cos/sin tables -----------------------
// cost/sint: (L, 32). j<16: angle = (l%48)*freq[j]; j>=16: angle=(l/48)*freq[j-16]
__global__ void rope_table_kernel(float* __restrict__ cost, float* __restrict__ sint) {
    int idx = blockIdx.x * blockDim.x + threadIdx.x;
    if (idx >= LTOK * 32) return;
    int j = idx & 31;
    int l = idx >> 5;
    float t = (j < 16) ? (float)(l % WG) : (float)(l / WG);
    int fi = j & 15;
    float freq = powf(10000.0f, -(float)fi / 16.0f);
    float ang = t * freq;
    cost[idx] = cosf(ang);
    sint[idx] = sinf(ang);
}

// --------------------------- k2/k6: SGEMM + bias ---------------------------
// C(MxN) = A(MxK) @ B(KxN) + bias(N).  BM=BN=128, BK=8, 256 thr, 8x8 micro.
// Requires M%128==0, N%128==0, K%8==0.
__global__ __launch_bounds__(256) void gemm_bias_kernel(
    const float* __restrict__ A, const float* __restrict__ B,
    const float* __restrict__ bias, float* __restrict__ C,
    int M, int N, int K)
{
    __shared__ float As[8][128];   // [k][m]
    __shared__ float Bs[8][128];   // [k][n]
    const int tid = threadIdx.x;
    const int bm = blockIdx.y * 128;
    const int bn = blockIdx.x * 128;
    const int ty = tid / 16;       // 0..15
    const int tx = tid % 16;       // 0..15

    const int arow = tid >> 1;           // 0..127
    const int acol = (tid & 1) * 4;      // 0 or 4
    const int brow = tid >> 5;           // 0..7
    const int bcol = (tid & 31) * 4;     // 0..124

    float acc[8][8];
    #pragma unroll
    for (int i = 0; i < 8; ++i)
        #pragma unroll
        for (int j = 0; j < 8; ++j) acc[i][j] = 0.0f;

    for (int k0 = 0; k0 < K; k0 += 8) {
        float4 av = *(const float4*)&A[(size_t)(bm + arow) * K + k0 + acol];
        float4 bv = *(const float4*)&B[(size_t)(k0 + brow) * N + bn + bcol];
        __syncthreads();
        As[acol + 0][arow] = av.x;
        As[acol + 1][arow] = av.y;
        As[acol + 2][arow] = av.z;
        As[acol + 3][arow] = av.w;
        *(float4*)&Bs[brow][bcol] = bv;
        __syncthreads();
        #pragma unroll
        for (int kk = 0; kk < 8; ++kk) {
            float ra[8], rb[8];
            float4 a0 = *(const float4*)&As[kk][ty * 4];
            float4 a1 = *(const float4*)&As[kk][64 + ty * 4];
            float4 b0 = *(const float4*)&Bs[kk][tx * 4];
            float4 b1 = *(const float4*)&Bs[kk][64 + tx * 4];
            ra[0]=a0.x; ra[1]=a0.y; ra[2]=a0.z; ra[3]=a0.w;
            ra[4]=a1.x; ra[5]=a1.y; ra[6]=a1.z; ra[7]=a1.w;
            rb[0]=b0.x; rb[1]=b0.y; rb[2]=b0.z; rb[3]=b0.w;
            rb[4]=b1.x; rb[5]=b1.y; rb[6]=b1.z; rb[7]=b1.w;
            #pragma unroll
            for (int i = 0; i < 8; ++i)
                #pragma unroll
                for (int j = 0; j < 8; ++j)
                    acc[i][j] += ra[i] * rb[j];
        }
    }
    // epilogue: rows {bm+ty*4+i, bm+64+ty*4+i}, cols {bn+tx*4+j, bn+64+tx*4+j}
    #pragma unroll
    for (int ih = 0; ih < 2; ++ih) {
        #pragma unroll
        for (int i = 0; i < 4; ++i) {
            int row = bm + ih * 64 + ty * 4 + i;
            #pragma unroll
            for (int jh = 0; jh < 2; ++jh) {
                int col = bn + jh * 64 + tx * 4;
                float4 o;
                o.x = acc[ih * 4 + i][jh * 4 + 0] + bias[col + 0];
                o.y = acc[ih * 4 + i][jh * 4 + 1] + bias[col + 1];
                o.z = acc[ih * 4 + i][jh * 4 + 2] + bias[col + 2];
                o.w = acc[ih * 4 + i][jh * 4 + 3] + bias[col + 3];
                *(float4*)&C[(size_t)row * N + col] = o;
            }
        }
    }
}

// --------------------------- k3: split qkv + rope --------------------------
// qkv_raw: (L, 2304) row-major -> q,k,v each [NH][L][HD]; rope on q,k.
__global__ void split_rope_kernel(
    const float* __restrict__ qkv_raw,
    const float* __restrict__ cost, const float* __restrict__ sint,
    float* __restrict__ q, float* __restrict__ k, float* __restrict__ v)
{
    int idx = blockIdx.x * blockDim.x + threadIdx.x;   // (l, h, pair j)
    if (idx >= LTOK * NH * 32) return;
    int j = idx & 31;
    int h = (idx >> 5) % NH;
    int l = idx / (32 * NH);
    const float* row = qkv_raw + (size_t)l * QKVN;
    float c = cost[l * 32 + j];
    float s = sint[l * 32 + j];
    size_t base = ((size_t)h * LTOK + l) * HD + 2 * j;

    float2 tq = *(const float2*)&row[h * HD + 2 * j];
    float2 tk = *(const float2*)&row[DIMC + h * HD + 2 * j];
    float2 tv = *(const float2*)&row[2 * DIMC + h * HD + 2 * j];

    float2 oq, ok;
    oq.x = tq.x * c - tq.y * s;
    oq.y = tq.x * s + tq.y * c;
    ok.x = tk.x * c - tk.y * s;
    ok.y = tk.x * s + tk.y * c;
    *(float2*)&q[base] = oq;
    *(float2*)&k[base] = ok;
    *(float2*)&v[base] = tv;
}

// --------------------------- k4: decomposed rel-pos bias -------------------
// rel_h[n][l][kh] = dot(q[n][l][:], rel_pos_h[h-kh+47][:]),  l=(h,w)
// rel_w[n][l][kw] = dot(q[n][l][:], rel_pos_w[w-kw+47][:])
__global__ __launch_bounds__(128) void relbias_kernel(
    const float* __restrict__ q,
    const float* __restrict__ rel_pos_h, const float* __restrict__ rel_pos_w,
    float* __restrict__ rel_h, float* __restrict__ rel_w)
{
    int n = blockIdx.y;
    int l = blockIdx.x;
    int h = l / WG, w = l % WG;
    __shared__ float qrow[HD];
    int t = threadIdx.x;
    if (t < HD) qrow[t] = q[((size_t)n * LTOK + l) * HD + t];
    __syncthreads();
    if (t < WG) {
        const float* bh = rel_pos_h + (size_t)(h - t + WG - 1) * HD;
        float sh = 0.0f;
        #pragma unroll
        for (int c = 0; c < HD; ++c) sh += qrow[c] * bh[c];
        rel_h[((size_t)n * LTOK + l) * WG + t] = sh;
    } else if (t >= 64 && t < 64 + WG) {
        int tw = t - 64;
        const float* bw = rel_pos_w + (size_t)(w - tw + WG - 1) * HD;
        float sw = 0.0f;
        #pragma unroll
        for (int c = 0; c < HD; ++c) sw += qrow[c] * bw[c];
        rel_w[((size_t)n * LTOK + l) * WG + tw] = sw;
    }
}

// --------------------------- k5: flash attention ---------------------------
// block = (head n, 32 query rows). 256 thr: thread (r=tid/8, g=tid%8).
// S-phase: thread owns keys g*8..g*8+7 of row r.  PV: dims g*8..g*8+7 of row r.
__global__ __launch_bounds__(256) void attn_kernel(
    const float* __restrict__ q, const float* __restrict__ k,
    const float* __restrict__ v, const float* __restrict__ rel_h,
    const float* __restrict__ rel_w, float* __restrict__ o)
{
    constexpr int BQ = 32, BKV = 64;
    __shared__ float qs[BQ][68];    // padded: rows 16B-aligned, broadcast reads
    __shared__ float ks[BKV][68];
    __shared__ float vs[BKV][68];
    __shared__ float ps[BQ][65];
    __shared__ float rh[BQ][48];
    __shared__ float rw[BQ][48];

    const int n = blockIdx.y;
    const int q0 = blockIdx.x * BQ;
    const int tid = threadIdx.x;
    const int r = tid >> 3;   // query row within tile
    const int g = tid & 7;    // key/dim group

    const float* qh = q + (size_t)n * LTOK * HD;
    const float* kh = k + (size_t)n * LTOK * HD;
    const float* vh = v + (size_t)n * LTOK * HD;

    // stage q tile (32x64) and rel bias rows (32x48 each)
    for (int t = tid; t < BQ * 16; t += 256) {
        int row = t >> 4, c4 = (t & 15) * 4;
        *(float4*)&qs[row][c4] = *(const float4*)&qh[(size_t)(q0 + row) * HD + c4];
    }
    for (int t = tid; t < BQ * 12; t += 256) {
        int row = t / 12, c4 = (t % 12) * 4;
        size_t rbase = ((size_t)n * LTOK + q0 + row) * WG + c4;
        *(float4*)&rh[row][c4] = *(const float4*)&rel_h[rbase];
        *(float4*)&rw[row][c4] = *(const float4*)&rel_w[rbase];
    }

    float m = -1e30f, lsum = 0.0f;
    float oacc[8];
    #pragma unroll
    for (int j = 0; j < 8; ++j) oacc[j] = 0.0f;

    for (int kt = 0; kt < LTOK / BKV; ++kt) {
        __syncthreads();   // prev iter done reading ks/vs; also covers qs staging
        for (int t = tid; t < BKV * 16; t += 256) {
            int row = t >> 4, c4 = (t & 15) * 4;
            size_t src = (size_t)(kt * BKV + row) * HD + c4;
            *(float4*)&ks[row][c4] = *(const float4*)&kh[src];
            *(float4*)&vs[row][c4] = *(const float4*)&vh[src];
        }
        __syncthreads();

        // S = q . k^T for keys g*8..g*8+7
        float s[8];
        #pragma unroll
        for (int j = 0; j < 8; ++j) s[j] = 0.0f;
        #pragma unroll
        for (int d4 = 0; d4 < 16; ++d4) {
            float4 qv = *(const float4*)&qs[r][d4 * 4];
            #pragma unroll
            for (int j = 0; j < 8; ++j) {
                float4 kv = *(const float4*)&ks[g * 8 + j][d4 * 4];
                s[j] += qv.x * kv.x + qv.y * kv.y + qv.z * kv.z + qv.w * kv.w;
            }
        }
        // scale + decomposed rel bias
        #pragma unroll
        for (int j = 0; j < 8; ++j) {
            int kk = kt * BKV + g * 8 + j;
            int khi = kk / WG;
            int kwi = kk - khi * WG;
            s[j] = s[j] * SCALE + rh[r][khi] + rw[r][kwi];
        }
        // online softmax: row reduce over 8 lanes of this row (lanes g=0..7)
        float mx = s[0];
        #pragma unroll
        for (int j = 1; j < 8; ++j) mx = fmaxf(mx, s[j]);
        mx = fmaxf(mx, __shfl_xor(mx, 1));
        mx = fmaxf(mx, __shfl_xor(mx, 2));
        mx = fmaxf(mx, __shfl_xor(mx, 4));
        float mnew = fmaxf(m, mx);
        float factor = __expf(m - mnew);
        float psum = 0.0f;
        #pragma unroll
        for (int j = 0; j < 8; ++j) {
            float p = __expf(s[j] - mnew);
            ps[r][g * 8 + j] = p;
            psum += p;
        }
        psum += __shfl_xor(psum, 1);
        psum += __shfl_xor(psum, 2);
        psum += __shfl_xor(psum, 4);
        lsum = lsum * factor + psum;
        m = mnew;
        #pragma unroll
        for (int j = 0; j < 8; ++j) oacc[j] *= factor;
        __syncthreads();   // ps visible to all

        // PV: accumulate dims g*8..g*8+7 of row r
        #pragma unroll 4
        for (int kk2 = 0; kk2 < BKV; ++kk2) {
            float p = ps[r][kk2];
            float4 v0 = *(const float4*)&vs[kk2][g * 8];
            float4 v1 = *(const float4*)&vs[kk2][g * 8 + 4];
            oacc[0] += p * v0.x; oacc[1] += p * v0.y;
            oacc[2] += p * v0.z; oacc[3] += p * v0.w;
            oacc[4] += p * v1.x; oacc[5] += p * v1.y;
            oacc[6] += p * v1.z; oacc[7] += p * v1.w;
        }
    }

    float inv = 1.0f / lsum;
    float4 o0, o1;
    o0.x = oacc[0] * inv; o0.y = oacc[1] * inv;
    o0.z = oacc[2] * inv; o0.w = oacc[3] * inv;
    o1.x = oacc[4] * inv; o1.y = oacc[5] * inv;
    o1.z = oacc[6] * inv; o1.w = oacc[7] * inv;
    size_t base = (size_t)(q0 + r) * DIMC + n * HD + g * 8;
    *(float4*)&o[base] = o0;
    *(float4*)&o[base + 4] = o1;
}

// ---------------------------------------------------------------------------
extern "C" void kernel_launch(void* const* d_in, const int* in_sizes, int n_in,
                              void* d_out, int out_size, void* d_ws, size_t ws_size,
                              hipStream_t stream) {
    (void)in_sizes; (void)n_in; (void)out_size; (void)ws_size;
    const float* x         = (const float*)d_in[0];   // (2304, 768)
    const float* w_qkv     = (const float*)d_in[1];   // (768, 2304)
    const float* b_qkv     = (const float*)d_in[2];   // (2304,)
    const float* w_proj    = (const float*)d_in[3];   // (768, 768)
    const float* b_proj    = (const float*)d_in[4];   // (768,)
    const float* rel_pos_h = (const float*)d_in[5];   // (95, 64)
    const float* rel_pos_w = (const float*)d_in[6];   // (95, 64)
    float* out = (float*)d_out;                       // (2304, 768)

    float* w = (float*)d_ws;
    float* qkv_raw = w;                                    // L*2304
    float* q     = qkv_raw + (size_t)LTOK * QKVN;          // NH*L*HD
    float* k     = q  + (size_t)NH * LTOK * HD;
    float* v     = k  + (size_t)NH * LTOK * HD;
    float* o     = v  + (size_t)NH * LTOK * HD;            // L*768
    float* rel_h = o  + (size_t)NH * LTOK * HD;            // NH*L*48
    float* rel_w = rel_h + (size_t)NH * LTOK * WG;
    float* cost  = rel_w + (size_t)NH * LTOK * WG;         // L*32
    float* sint  = cost + (size_t)LTOK * 32;
    // total ~15.2M floats = 61 MB of d_ws

    rope_table_kernel<<<(LTOK * 32 + 255) / 256, 256, 0, stream>>>(cost, sint);

    dim3 gq(QKVN / 128, LTOK / 128);
    gemm_bias_kernel<<<gq, 256, 0, stream>>>(x, w_qkv, b_qkv, qkv_raw,
                                             LTOK, QKVN, DIMC);

    split_rope_kernel<<<(LTOK * NH * 32 + 255) / 256, 256, 0, stream>>>(
        qkv_raw, cost, sint, q, k, v);

    relbias_kernel<<<dim3(LTOK, NH), 128, 0, stream>>>(
        q, rel_pos_h, rel_pos_w, rel_h, rel_w);

    attn_kernel<<<dim3(LTOK / 32, NH), 256, 0, stream>>>(
        q, k, v, rel_h, rel_w, o);

    dim3 gp(DIMC / 128, LTOK / 128);
    gemm_bias_kernel<<<gp, 256, 0, stream>>>(o, w_proj, b_proj, out,
                                             LTOK, DIMC, DIMC);
}

// Round 2
// 246.475 us; speedup vs baseline: 4.5643x; 4.5643x over previous
//
#include <hip/hip_runtime.h>
#include <hip/hip_bf16.h>

// ---------------------------------------------------------------------------
// TRTAttention round 2: bf16 MFMA everywhere (QKV gemm, QK^T, PV, proj gemm).
// L=2304 (48x48), dim=768, 12 heads x 64. fp32 accumulate, bf16 operands.
// ---------------------------------------------------------------------------

typedef short bf16x8 __attribute__((ext_vector_type(8)));
typedef float f32x4  __attribute__((ext_vector_type(4)));

namespace {
constexpr int LTOK = 2304;
constexpr int DIMC = 768;
constexpr int NH   = 12;
constexpr int HD   = 64;
constexpr int WG   = 48;
constexpr int QKVN = 2304;
constexpr float SCALE = 0.125f;
}

__device__ __forceinline__ short f2b(float f) {
    __hip_bfloat16 h = __float2bfloat16(f);
    return *reinterpret_cast<short*>(&h);
}
__device__ __forceinline__ float b2f(short s) {
    return __uint_as_float(((unsigned)(unsigned short)s) << 16);
}

// --------------------------- rope tables -----------------------------------
__global__ void rope_table_kernel(float* __restrict__ cost, float* __restrict__ sint) {
    int idx = blockIdx.x * blockDim.x + threadIdx.x;
    if (idx >= LTOK * 32) return;
    int j = idx & 31;
    int l = idx >> 5;
    float t = (j < 16) ? (float)(l % WG) : (float)(l / WG);
    int fi = j & 15;
    float freq = powf(10000.0f, -(float)fi / 16.0f);
    float ang = t * freq;
    cost[idx] = cosf(ang);
    sint[idx] = sinf(ang);
}

// --------------------------- fp32 -> bf16 cast -----------------------------
__global__ void cast_bf16_kernel(const float* __restrict__ in, short* __restrict__ out, int n8) {
    int i = blockIdx.x * blockDim.x + threadIdx.x;
    if (i >= n8) return;
    float4 a = ((const float4*)in)[2 * i];
    float4 b = ((const float4*)in)[2 * i + 1];
    bf16x8 o;
    o[0] = f2b(a.x); o[1] = f2b(a.y); o[2] = f2b(a.z); o[3] = f2b(a.w);
    o[4] = f2b(b.x); o[5] = f2b(b.y); o[6] = f2b(b.z); o[7] = f2b(b.w);
    ((bf16x8*)out)[i] = o;
}

// ----------------- fp32 (R,C) -> bf16 (C,R) transpose+cast -----------------
__global__ __launch_bounds__(256) void transpose_cast_kernel(
    const float* __restrict__ in, short* __restrict__ out, int R, int C) {
    __shared__ float ts[32][36];
    const int c0 = blockIdx.x * 32, r0 = blockIdx.y * 32;
    const int t = threadIdx.x;
    {
        int r = t >> 3, cb = (t & 7) * 4;
        float4 v = *(const float4*)&in[(size_t)(r0 + r) * C + c0 + cb];
        ts[r][cb] = v.x; ts[r][cb + 1] = v.y; ts[r][cb + 2] = v.z; ts[r][cb + 3] = v.w;
    }
    __syncthreads();
    {
        int oc = t >> 3, rb = (t & 7) * 4;
        short4 s;
        s.x = f2b(ts[rb][oc]);     s.y = f2b(ts[rb + 1][oc]);
        s.z = f2b(ts[rb + 2][oc]); s.w = f2b(ts[rb + 3][oc]);
        *(short4*)&out[(size_t)(c0 + oc) * R + r0 + rb] = s;
    }
}

// --------------------------- bf16 MFMA GEMM --------------------------------
// C(MxN) fp32 = A(MxK)bf16 @ Bt(NxK)bf16^T + bias(N). 128x128 tile, BK=64.
__global__ __launch_bounds__(256) void gemm_bf16_kernel(
    const short* __restrict__ A, const short* __restrict__ Bt,
    const float* __restrict__ bias, float* __restrict__ C,
    int M, int N, int K)
{
    __shared__ short As[128][72];
    __shared__ short Bs[128][72];
    const int tid = threadIdx.x;
    const int bm = blockIdx.y * 128, bn = blockIdx.x * 128;
    const int w = tid >> 6, l = tid & 63;
    const int wr = w >> 1, wc = w & 1;
    const int lm = l & 15, lk = (l >> 4) * 8;

    f32x4 acc[4][4];
    const f32x4 zf = {0.f, 0.f, 0.f, 0.f};
    #pragma unroll
    for (int m = 0; m < 4; ++m)
        #pragma unroll
        for (int n = 0; n < 4; ++n) acc[m][n] = zf;

    for (int k0 = 0; k0 < K; k0 += 64) {
        __syncthreads();
        #pragma unroll
        for (int p = 0; p < 4; ++p) {
            int flat = tid + p * 256;
            int row = flat >> 3, colb = (flat & 7) * 8;
            *(bf16x8*)&As[row][colb] = *(const bf16x8*)&A[(size_t)(bm + row) * K + k0 + colb];
            *(bf16x8*)&Bs[row][colb] = *(const bf16x8*)&Bt[(size_t)(bn + row) * K + k0 + colb];
        }
        __syncthreads();
        #pragma unroll
        for (int kh = 0; kh < 2; ++kh) {
            bf16x8 a[4], b[4];
            #pragma unroll
            for (int m = 0; m < 4; ++m)
                a[m] = *(const bf16x8*)&As[wr * 64 + m * 16 + lm][kh * 32 + lk];
            #pragma unroll
            for (int n = 0; n < 4; ++n)
                b[n] = *(const bf16x8*)&Bs[wc * 64 + n * 16 + lm][kh * 32 + lk];
            #pragma unroll
            for (int m = 0; m < 4; ++m)
                #pragma unroll
                for (int n = 0; n < 4; ++n)
                    acc[m][n] = __builtin_amdgcn_mfma_f32_16x16x32_bf16(a[m], b[n], acc[m][n], 0, 0, 0);
        }
    }
    const int orow = (l >> 4) * 4;
    #pragma unroll
    for (int m = 0; m < 4; ++m) {
        #pragma unroll
        for (int n = 0; n < 4; ++n) {
            int col = bn + wc * 64 + n * 16 + lm;
            float bv = bias[col];
            #pragma unroll
            for (int r = 0; r < 4; ++r) {
                int row = bm + wr * 64 + m * 16 + orow + r;
                C[(size_t)row * N + col] = acc[m][n][r] + bv;
            }
        }
    }
}

// ------------------- split qkv + rope -> bf16 q,k,vT -----------------------
// grid (L/64, NH), 256 thr. q,k: [h][l][d] bf16 (rotated). vT: [h][d][l] bf16.
__global__ __launch_bounds__(256) void split_rope_kernel(
    const float* __restrict__ qkv_raw,
    const float* __restrict__ cost, const float* __restrict__ sint,
    short* __restrict__ q, short* __restrict__ k, short* __restrict__ vT)
{
    __shared__ short vt_s[64][72];
    const int h = blockIdx.y;
    const int l0 = blockIdx.x * 64;
    const int t = threadIdx.x;
    const int tok = t >> 2, dq = (t & 3) * 16;
    const int l = l0 + tok;
    const float* row = qkv_raw + (size_t)l * QKVN + h * HD;

    bf16x8 qv[2], kv[2];
    #pragma unroll
    for (int i = 0; i < 16; i += 4) {
        int d = dq + i;
        float4 tq = *(const float4*)&row[d];
        float4 tk = *(const float4*)&row[DIMC + d];
        float4 tv = *(const float4*)&row[2 * DIMC + d];
        float2 c01 = *(const float2*)&cost[l * 32 + d / 2];
        float2 s01 = *(const float2*)&sint[l * 32 + d / 2];
        qv[i >> 3][(i & 7) + 0] = f2b(tq.x * c01.x - tq.y * s01.x);
        qv[i >> 3][(i & 7) + 1] = f2b(tq.x * s01.x + tq.y * c01.x);
        qv[i >> 3][(i & 7) + 2] = f2b(tq.z * c01.y - tq.w * s01.y);
        qv[i >> 3][(i & 7) + 3] = f2b(tq.z * s01.y + tq.w * c01.y);
        kv[i >> 3][(i & 7) + 0] = f2b(tk.x * c01.x - tk.y * s01.x);
        kv[i >> 3][(i & 7) + 1] = f2b(tk.x * s01.x + tk.y * c01.x);
        kv[i >> 3][(i & 7) + 2] = f2b(tk.z * c01.y - tk.w * s01.y);
        kv[i >> 3][(i & 7) + 3] = f2b(tk.z * s01.y + tk.w * c01.y);
        vt_s[d + 0][tok] = f2b(tv.x);
        vt_s[d + 1][tok] = f2b(tv.y);
        vt_s[d + 2][tok] = f2b(tv.z);
        vt_s[d + 3][tok] = f2b(tv.w);
    }
    size_t qbase = ((size_t)h * LTOK + l) * HD + dq;
    *(bf16x8*)&q[qbase]     = qv[0];
    *(bf16x8*)&q[qbase + 8] = qv[1];
    *(bf16x8*)&k[qbase]     = kv[0];
    *(bf16x8*)&k[qbase + 8] = kv[1];
    __syncthreads();
    const int drow = t >> 2, lq = (t & 3) * 16;
    bf16x8 v0 = *(bf16x8*)&vt_s[drow][lq];
    bf16x8 v1 = *(bf16x8*)&vt_s[drow][lq + 8];
    size_t vbase = ((size_t)h * HD + drow) * LTOK + l0 + lq;
    *(bf16x8*)&vT[vbase]     = v0;
    *(bf16x8*)&vT[vbase + 8] = v1;
}

// --------------------------- decomposed rel-pos bias -----------------------
// grid (L/16, NH), 256 thr. rel_h[n][l][kh] = q[n][l][:] . rel_pos_h[h-kh+47]
__global__ __launch_bounds__(256) void relbias_kernel(
    const short* __restrict__ q,
    const float* __restrict__ rel_pos_h, const float* __restrict__ rel_pos_w,
    float* __restrict__ rel_h, float* __restrict__ rel_w)
{
    __shared__ float qs2[16][68];
    const int nb = blockIdx.y;
    const int l0 = blockIdx.x * 16;
    const int t = threadIdx.x;
    {
        int flat = t * 4;
        int row = flat >> 6, col = flat & 63;
        const short* src = &q[((size_t)nb * LTOK + l0 + row) * HD + col];
        qs2[row][col] = b2f(src[0]); qs2[row][col + 1] = b2f(src[1]);
        qs2[row][col + 2] = b2f(src[2]); qs2[row][col + 3] = b2f(src[3]);
    }
    __syncthreads();
    const int ti = t >> 4, ks2 = t & 15;
    const int ll = l0 + ti;
    const int hh = ll / WG, ww = ll % WG;
    for (int ko = ks2; ko < 96; ko += 16) {
        bool ish = ko < 48;
        int kk = ish ? ko : ko - 48;
        int rp = (ish ? hh : ww) - kk + WG - 1;
        const float* br = (ish ? rel_pos_h : rel_pos_w) + (size_t)rp * HD;
        float s = 0.f;
        #pragma unroll
        for (int c = 0; c < HD; ++c) s += qs2[ti][c] * br[c];
        float* dst = ish ? rel_h : rel_w;
        dst[((size_t)nb * LTOK + ll) * WG + kk] = s;
    }
}

// --------------------------- flash attention (MFMA) ------------------------
// grid (L/64, NH), 256 thr = 4 waves; wave w owns q-rows [w*16, w*16+16).
__global__ __launch_bounds__(256) void attn_kernel(
    const short* __restrict__ q, const short* __restrict__ k,
    const short* __restrict__ vT, const float* __restrict__ rel_h,
    const float* __restrict__ rel_w, short* __restrict__ o)
{
    __shared__ short ks[64][72];     // [key][d]
    __shared__ short vs[64][72];     // [d][key]
    __shared__ float rh[64][48];
    __shared__ float rw[64][48];
    __shared__ short ps[4][16][72];  // per-wave P / O staging

    const int n = blockIdx.y;
    const int q0 = blockIdx.x * 64;
    const int tid = threadIdx.x;
    const int w = tid >> 6, l = tid & 63;
    const int lm = l & 15, lk = (l >> 4) * 8;
    const int rbase = (l >> 4) * 4;

    const short* qh = q + (size_t)n * LTOK * HD;
    const short* kh = k + (size_t)n * LTOK * HD;
    const short* vh = vT + (size_t)n * HD * LTOK;

    // Q fragments (rows q0 + w*16 + lm), resident in regs for whole kernel
    bf16x8 qf[2];
    #pragma unroll
    for (int kk = 0; kk < 2; ++kk)
        qf[kk] = *(const bf16x8*)&qh[(size_t)(q0 + w * 16 + lm) * HD + kk * 32 + lk];

    // stage rel bias rows for this q-block
    for (int t = tid; t < 64 * 12; t += 256) {
        int row = t / 12, c4 = (t % 12) * 4;
        size_t rb = ((size_t)n * LTOK + q0 + row) * WG + c4;
        *(float4*)&rh[row][c4] = *(const float4*)&rel_h[rb];
        *(float4*)&rw[row][c4] = *(const float4*)&rel_w[rb];
    }

    float m0[4], lsum[4];
    f32x4 oacc[4];
    const f32x4 zf = {0.f, 0.f, 0.f, 0.f};
    #pragma unroll
    for (int r = 0; r < 4; ++r) { m0[r] = -1e30f; lsum[r] = 0.f; }
    #pragma unroll
    for (int d = 0; d < 4; ++d) oacc[d] = zf;

    for (int kt = 0; kt < LTOK / 64; ++kt) {
        __syncthreads();
        #pragma unroll
        for (int p = 0; p < 2; ++p) {
            int flat = tid + p * 256;
            int row = flat >> 3, colb = (flat & 7) * 8;
            *(bf16x8*)&ks[row][colb] = *(const bf16x8*)&kh[(size_t)(kt * 64 + row) * HD + colb];
            *(bf16x8*)&vs[row][colb] = *(const bf16x8*)&vh[(size_t)row * LTOK + kt * 64 + colb];
        }
        __syncthreads();

        // S tile: 16 q-rows x 64 keys per wave
        f32x4 sf[4];
        #pragma unroll
        for (int f = 0; f < 4; ++f) {
            sf[f] = zf;
            #pragma unroll
            for (int kk = 0; kk < 2; ++kk) {
                bf16x8 kf = *(const bf16x8*)&ks[f * 16 + lm][kk * 32 + lk];
                sf[f] = __builtin_amdgcn_mfma_f32_16x16x32_bf16(qf[kk], kf, sf[f], 0, 0, 0);
            }
        }
        // scale + decomposed rel bias  (S row = w*16 + rbase + r, col = key)
        #pragma unroll
        for (int f = 0; f < 4; ++f) {
            int key = kt * 64 + f * 16 + lm;
            int khi = key / 48, kwi = key % 48;
            #pragma unroll
            for (int r = 0; r < 4; ++r)
                sf[f][r] = sf[f][r] * SCALE + rh[w * 16 + rbase + r][khi]
                                            + rw[w * 16 + rbase + r][kwi];
        }
        // online softmax (row stats shared across the 16-lane col group)
        float fac[4], rsum[4];
        #pragma unroll
        for (int r = 0; r < 4; ++r) {
            float mx = fmaxf(fmaxf(sf[0][r], sf[1][r]), fmaxf(sf[2][r], sf[3][r]));
            mx = fmaxf(mx, __shfl_xor(mx, 1));
            mx = fmaxf(mx, __shfl_xor(mx, 2));
            mx = fmaxf(mx, __shfl_xor(mx, 4));
            mx = fmaxf(mx, __shfl_xor(mx, 8));
            float mnew = fmaxf(m0[r], mx);
            fac[r] = __expf(m0[r] - mnew);
            m0[r] = mnew;
            rsum[r] = 0.f;
        }
        #pragma unroll
        for (int f = 0; f < 4; ++f)
            #pragma unroll
            for (int r = 0; r < 4; ++r) {
                float p = __expf(sf[f][r] - m0[r]);
                rsum[r] += p;
                ps[w][rbase + r][f * 16 + lm] = f2b(p);
            }
        #pragma unroll
        for (int r = 0; r < 4; ++r) {
            float s = rsum[r];
            s += __shfl_xor(s, 1); s += __shfl_xor(s, 2);
            s += __shfl_xor(s, 4); s += __shfl_xor(s, 8);
            lsum[r] = lsum[r] * fac[r] + s;
        }
        #pragma unroll
        for (int d = 0; d < 4; ++d)
            #pragma unroll
            for (int r = 0; r < 4; ++r)
                oacc[d][r] *= fac[r];
        // PV: O += P @ V  (A-frag from ps, B-frag from vs)
        #pragma unroll
        for (int kk = 0; kk < 2; ++kk) {
            bf16x8 pf = *(const bf16x8*)&ps[w][lm][kk * 32 + lk];
            #pragma unroll
            for (int d = 0; d < 4; ++d) {
                bf16x8 vf = *(const bf16x8*)&vs[d * 16 + lm][kk * 32 + lk];
                oacc[d] = __builtin_amdgcn_mfma_f32_16x16x32_bf16(pf, vf, oacc[d], 0, 0, 0);
            }
        }
    }

    // epilogue: normalize, assemble via wave-private LDS, coalesced bf16 write
    float inv[4];
    #pragma unroll
    for (int r = 0; r < 4; ++r) inv[r] = 1.0f / lsum[r];
    #pragma unroll
    for (int d = 0; d < 4; ++d)
        #pragma unroll
        for (int r = 0; r < 4; ++r)
            ps[w][rbase + r][d * 16 + lm] = f2b(oacc[d][r] * inv[r]);
    const int orow = l >> 2, ocb = (l & 3) * 16;
    bf16x8 o0 = *(bf16x8*)&ps[w][orow][ocb];
    bf16x8 o1 = *(bf16x8*)&ps[w][orow][ocb + 8];
    size_t obase = (size_t)(q0 + w * 16 + orow) * DIMC + n * HD + ocb;
    *(bf16x8*)&o[obase]     = o0;
    *(bf16x8*)&o[obase + 8] = o1;
}

// ---------------------------------------------------------------------------
extern "C" void kernel_launch(void* const* d_in, const int* in_sizes, int n_in,
                              void* d_out, int out_size, void* d_ws, size_t ws_size,
                              hipStream_t stream) {
    (void)in_sizes; (void)n_in; (void)out_size; (void)ws_size;
    const float* x         = (const float*)d_in[0];   // (2304, 768)
    const float* w_qkv     = (const float*)d_in[1];   // (768, 2304)
    const float* b_qkv     = (const float*)d_in[2];   // (2304,)
    const float* w_proj    = (const float*)d_in[3];   // (768, 768)
    const float* b_proj    = (const float*)d_in[4];   // (768,)
    const float* rel_pos_h = (const float*)d_in[5];   // (95, 64)
    const float* rel_pos_w = (const float*)d_in[6];   // (95, 64)
    float* out = (float*)d_out;                       // (2304, 768) fp32

    float* qkv_raw = (float*)d_ws;                         // L*2304 f32
    float* rel_h   = qkv_raw + (size_t)LTOK * QKVN;        // NH*L*48
    float* rel_w   = rel_h + (size_t)NH * LTOK * WG;
    float* cost    = rel_w + (size_t)NH * LTOK * WG;       // L*32
    float* sint    = cost + (size_t)LTOK * 32;
    short* xb      = (short*)(sint + (size_t)LTOK * 32);   // L*768 bf16
    short* wqkvT   = xb + (size_t)LTOK * DIMC;             // 2304*768
    short* wprojT  = wqkvT + (size_t)QKVN * DIMC;          // 768*768
    short* qb      = wprojT + (size_t)DIMC * DIMC;         // NH*L*64
    short* kb      = qb + (size_t)NH * LTOK * HD;
    short* vTb     = kb + (size_t)NH * LTOK * HD;          // [h][d][L]
    short* ob      = vTb + (size_t)NH * LTOK * HD;         // L*768
    // total ~55 MB of d_ws

    rope_table_kernel<<<(LTOK * 32 + 255) / 256, 256, 0, stream>>>(cost, sint);

    cast_bf16_kernel<<<(LTOK * DIMC / 8 + 255) / 256, 256, 0, stream>>>(
        x, xb, LTOK * DIMC / 8);
    transpose_cast_kernel<<<dim3(QKVN / 32, DIMC / 32), 256, 0, stream>>>(
        w_qkv, wqkvT, DIMC, QKVN);
    transpose_cast_kernel<<<dim3(DIMC / 32, DIMC / 32), 256, 0, stream>>>(
        w_proj, wprojT, DIMC, DIMC);

    gemm_bf16_kernel<<<dim3(QKVN / 128, LTOK / 128), 256, 0, stream>>>(
        xb, wqkvT, b_qkv, qkv_raw, LTOK, QKVN, DIMC);

    split_rope_kernel<<<dim3(LTOK / 64, NH), 256, 0, stream>>>(
        qkv_raw, cost, sint, qb, kb, vTb);

    relbias_kernel<<<dim3(LTOK / 16, NH), 256, 0, stream>>>(
        qb, rel_pos_h, rel_pos_w, rel_h, rel_w);

    attn_kernel<<<dim3(LTOK / 64, NH), 256, 0, stream>>>(
        qb, kb, vTb, rel_h, rel_w, ob);

    gemm_bf16_kernel<<<dim3(DIMC / 128, LTOK / 128), 256, 0, stream>>>(
        ob, wprojT, b_proj, out, LTOK, DIMC, DIMC);
}

// Round 3
// 183.687 us; speedup vs baseline: 6.1244x; 1.3418x over previous
//
#include <hip/hip_runtime.h>
#include <hip/hip_bf16.h>

// ---------------------------------------------------------------------------
// TRTAttention round 3: split-K flash attn (occupancy), gl_lds GEMMs, LDS relbias.
// L=2304 (48x48), dim=768, 12 heads x 64. bf16 MFMA, fp32 accumulate.
// ---------------------------------------------------------------------------

typedef short bf16x8 __attribute__((ext_vector_type(8)));
typedef float f32x4  __attribute__((ext_vector_type(4)));

namespace {
constexpr int LTOK = 2304;
constexpr int DIMC = 768;
constexpr int NH   = 12;
constexpr int HD   = 64;
constexpr int WG   = 48;
constexpr int QKVN = 2304;
constexpr int NSPLIT = 3;
constexpr int KPS  = LTOK / NSPLIT;   // 768 keys per split
constexpr int NQB  = LTOK / 64;       // 36 q-blocks
constexpr float SCALE = 0.125f;
}

__device__ __forceinline__ short f2b(float f) {
    __hip_bfloat16 h = __float2bfloat16(f);
    return *reinterpret_cast<short*>(&h);
}
__device__ __forceinline__ float b2f(short s) {
    return __uint_as_float(((unsigned)(unsigned short)s) << 16);
}
__device__ __forceinline__ void load16_to_lds(const short* g, short* l) {
    __builtin_amdgcn_global_load_lds(
        (__attribute__((address_space(1))) void*)g,
        (__attribute__((address_space(3))) void*)l,
        16, 0, 0);
}

// --------------------------- rope tables -----------------------------------
__global__ void rope_table_kernel(float* __restrict__ cost, float* __restrict__ sint) {
    int idx = blockIdx.x * blockDim.x + threadIdx.x;
    if (idx >= LTOK * 32) return;
    int j = idx & 31;
    int l = idx >> 5;
    float t = (j < 16) ? (float)(l % WG) : (float)(l / WG);
    int fi = j & 15;
    float freq = powf(10000.0f, -(float)fi / 16.0f);
    float ang = t * freq;
    cost[idx] = cosf(ang);
    sint[idx] = sinf(ang);
}

// --------------------------- fp32 -> bf16 cast -----------------------------
__global__ void cast_bf16_kernel(const float* __restrict__ in, short* __restrict__ out, int n8) {
    int i = blockIdx.x * blockDim.x + threadIdx.x;
    if (i >= n8) return;
    float4 a = ((const float4*)in)[2 * i];
    float4 b = ((const float4*)in)[2 * i + 1];
    bf16x8 o;
    o[0] = f2b(a.x); o[1] = f2b(a.y); o[2] = f2b(a.z); o[3] = f2b(a.w);
    o[4] = f2b(b.x); o[5] = f2b(b.y); o[6] = f2b(b.z); o[7] = f2b(b.w);
    ((bf16x8*)out)[i] = o;
}

// ----------------- fp32 (R,C) -> bf16 (C,R) transpose+cast -----------------
__global__ __launch_bounds__(256) void transpose_cast_kernel(
    const float* __restrict__ in, short* __restrict__ out, int R, int C) {
    __shared__ float ts[32][36];
    const int c0 = blockIdx.x * 32, r0 = blockIdx.y * 32;
    const int t = threadIdx.x;
    {
        int r = t >> 3, cb = (t & 7) * 4;
        float4 v = *(const float4*)&in[(size_t)(r0 + r) * C + c0 + cb];
        ts[r][cb] = v.x; ts[r][cb + 1] = v.y; ts[r][cb + 2] = v.z; ts[r][cb + 3] = v.w;
    }
    __syncthreads();
    {
        int oc = t >> 3, rb = (t & 7) * 4;
        short4 s;
        s.x = f2b(ts[rb][oc]);     s.y = f2b(ts[rb + 1][oc]);
        s.z = f2b(ts[rb + 2][oc]); s.w = f2b(ts[rb + 3][oc]);
        *(short4*)&out[(size_t)(c0 + oc) * R + r0 + rb] = s;
    }
}

// --------------------------- bf16 MFMA GEMM (m97-style) --------------------
// C(MxN) fp32 = A(MxK)bf16 @ Bt(NxK)bf16^T + bias(N). 128x128 tile, BK=64,
// linear LDS + global_load_lds width-16 staging.
__global__ __launch_bounds__(256) void gemm_bf16_kernel(
    const short* __restrict__ A, const short* __restrict__ Bt,
    const float* __restrict__ bias, float* __restrict__ C,
    int M, int N, int K)
{
    __shared__ short As[128 * 64];
    __shared__ short Bs[128 * 64];
    const int tid = threadIdx.x;
    const int bm = blockIdx.y * 128, bn = blockIdx.x * 128;
    const int w = tid >> 6, l = tid & 63;
    const int wr = w >> 1, wc = w & 1;
    const int lm = l & 15, lk = (l >> 4) * 8;

    f32x4 acc[4][4];
    const f32x4 zf = {0.f, 0.f, 0.f, 0.f};
    #pragma unroll
    for (int m = 0; m < 4; ++m)
        #pragma unroll
        for (int n = 0; n < 4; ++n) acc[m][n] = zf;

    for (int k0 = 0; k0 < K; k0 += 64) {
        __syncthreads();
        #pragma unroll
        for (int p = 0; p < 4; ++p) {
            int f = tid + p * 256;
            int row = f >> 3, c8 = (f & 7) * 8;
            load16_to_lds(&A[(size_t)(bm + row) * K + k0 + c8], &As[f * 8]);
            load16_to_lds(&Bt[(size_t)(bn + row) * K + k0 + c8], &Bs[f * 8]);
        }
        __syncthreads();
        #pragma unroll
        for (int kh = 0; kh < 2; ++kh) {
            bf16x8 a[4], b[4];
            #pragma unroll
            for (int m = 0; m < 4; ++m)
                a[m] = *(const bf16x8*)&As[(wr * 64 + m * 16 + lm) * 64 + kh * 32 + lk];
            #pragma unroll
            for (int n = 0; n < 4; ++n)
                b[n] = *(const bf16x8*)&Bs[(wc * 64 + n * 16 + lm) * 64 + kh * 32 + lk];
            #pragma unroll
            for (int m = 0; m < 4; ++m)
                #pragma unroll
                for (int n = 0; n < 4; ++n)
                    acc[m][n] = __builtin_amdgcn_mfma_f32_16x16x32_bf16(a[m], b[n], acc[m][n], 0, 0, 0);
        }
    }
    const int orow = (l >> 4) * 4;
    #pragma unroll
    for (int m = 0; m < 4; ++m) {
        #pragma unroll
        for (int n = 0; n < 4; ++n) {
            int col = bn + wc * 64 + n * 16 + lm;
            float bv = bias[col];
            #pragma unroll
            for (int r = 0; r < 4; ++r) {
                int row = bm + wr * 64 + m * 16 + orow + r;
                C[(size_t)row * N + col] = acc[m][n][r] + bv;
            }
        }
    }
}

// ------------------- split qkv + rope -> bf16 q,k,vT -----------------------
__global__ __launch_bounds__(256) void split_rope_kernel(
    const float* __restrict__ qkv_raw,
    const float* __restrict__ cost, const float* __restrict__ sint,
    short* __restrict__ q, short* __restrict__ k, short* __restrict__ vT)
{
    __shared__ short vt_s[64][72];
    const int h = blockIdx.y;
    const int l0 = blockIdx.x * 64;
    const int t = threadIdx.x;
    const int tok = t >> 2, dq = (t & 3) * 16;
    const int l = l0 + tok;
    const float* row = qkv_raw + (size_t)l * QKVN + h * HD;

    bf16x8 qv[2], kv[2];
    #pragma unroll
    for (int i = 0; i < 16; i += 4) {
        int d = dq + i;
        float4 tq = *(const float4*)&row[d];
        float4 tk = *(const float4*)&row[DIMC + d];
        float4 tv = *(const float4*)&row[2 * DIMC + d];
        float2 c01 = *(const float2*)&cost[l * 32 + d / 2];
        float2 s01 = *(const float2*)&sint[l * 32 + d / 2];
        qv[i >> 3][(i & 7) + 0] = f2b(tq.x * c01.x - tq.y * s01.x);
        qv[i >> 3][(i & 7) + 1] = f2b(tq.x * s01.x + tq.y * c01.x);
        qv[i >> 3][(i & 7) + 2] = f2b(tq.z * c01.y - tq.w * s01.y);
        qv[i >> 3][(i & 7) + 3] = f2b(tq.z * s01.y + tq.w * c01.y);
        kv[i >> 3][(i & 7) + 0] = f2b(tk.x * c01.x - tk.y * s01.x);
        kv[i >> 3][(i & 7) + 1] = f2b(tk.x * s01.x + tk.y * c01.x);
        kv[i >> 3][(i & 7) + 2] = f2b(tk.z * c01.y - tk.w * s01.y);
        kv[i >> 3][(i & 7) + 3] = f2b(tk.z * s01.y + tk.w * c01.y);
        vt_s[d + 0][tok] = f2b(tv.x);
        vt_s[d + 1][tok] = f2b(tv.y);
        vt_s[d + 2][tok] = f2b(tv.z);
        vt_s[d + 3][tok] = f2b(tv.w);
    }
    size_t qbase = ((size_t)h * LTOK + l) * HD + dq;
    *(bf16x8*)&q[qbase]     = qv[0];
    *(bf16x8*)&q[qbase + 8] = qv[1];
    *(bf16x8*)&k[qbase]     = kv[0];
    *(bf16x8*)&k[qbase + 8] = kv[1];
    __syncthreads();
    const int drow = t >> 2, lq = (t & 3) * 16;
    bf16x8 v0 = *(bf16x8*)&vt_s[drow][lq];
    bf16x8 v1 = *(bf16x8*)&vt_s[drow][lq + 8];
    size_t vbase = ((size_t)h * HD + drow) * LTOK + l0 + lq;
    *(bf16x8*)&vT[vbase]     = v0;
    *(bf16x8*)&vT[vbase + 8] = v1;
}

// --------------------------- decomposed rel-pos bias -----------------------
// block = 16 q-rows of one head (single h, contiguous w-range by construction).
// Stage needed rel_pos windows in LDS, vectorized f32x4 dots.
__global__ __launch_bounds__(256) void relbias_kernel(
    const short* __restrict__ q,
    const float* __restrict__ rel_pos_h, const float* __restrict__ rel_pos_w,
    float* __restrict__ rel_h, float* __restrict__ rel_w)
{
    __shared__ float qs2[16][68];
    __shared__ float rph_s[48][68];   // table rows h0 .. h0+47
    __shared__ float rpw_s[63][68];   // table rows w0 .. w0+62
    const int nb = blockIdx.y;
    const int l0 = blockIdx.x * 16;
    const int h0 = l0 / WG, w0 = l0 % WG;
    const int t = threadIdx.x;
    {
        int flat = t * 4;
        int row = flat >> 6, col = flat & 63;
        const short* src = &q[((size_t)nb * LTOK + l0 + row) * HD + col];
        qs2[row][col] = b2f(src[0]); qs2[row][col + 1] = b2f(src[1]);
        qs2[row][col + 2] = b2f(src[2]); qs2[row][col + 3] = b2f(src[3]);
    }
    for (int i = t; i < (48 + 63) * 16; i += 256) {
        int rr = i >> 4, c4 = (i & 15) * 4;
        if (rr < 48)
            *(float4*)&rph_s[rr][c4] = *(const float4*)&rel_pos_h[(size_t)(h0 + rr) * HD + c4];
        else
            *(float4*)&rpw_s[rr - 48][c4] = *(const float4*)&rel_pos_w[(size_t)(w0 + rr - 48) * HD + c4];
    }
    __syncthreads();
    const int ti = t >> 4, kg = t & 15;
    for (int ko = kg; ko < 96; ko += 16) {
        bool ish = ko < 48;
        int kk = ish ? ko : ko - 48;
        // rel_h: table row (h0+47-kk) -> staged 47-kk ; rel_w: (w0+ti+47-kk) -> ti+47-kk
        const float* br = ish ? &rph_s[47 - kk][0] : &rpw_s[ti + 47 - kk][0];
        float s = 0.f;
        #pragma unroll
        for (int c = 0; c < HD; c += 4) {
            float4 a = *(const float4*)&qs2[ti][c];
            float4 b = *(const float4*)&br[c];
            s += a.x * b.x + a.y * b.y + a.z * b.z + a.w * b.w;
        }
        (ish ? rel_h : rel_w)[((size_t)nb * LTOK + l0 + ti) * WG + kk] = s;
    }
}

// --------------------------- split-K flash attention -----------------------
// grid (36, 12, 3): block = (qblock 64 rows, head, key-split of 768 keys).
// 4 waves; wave w owns q-rows [w*16, w*16+16). Writes UNNORMALIZED partials.
__global__ __launch_bounds__(256) void attn_kernel(
    const short* __restrict__ q, const short* __restrict__ k,
    const short* __restrict__ vT, const float* __restrict__ rel_h,
    const float* __restrict__ rel_w, float* __restrict__ o_part,
    float* __restrict__ ml)
{
    __shared__ short ks[64][72];     // [key][d]
    __shared__ short vs[64][72];     // [d][key]
    __shared__ short rhb[64][48];    // bf16 rel bias rows
    __shared__ short rwb[64][48];
    __shared__ short ps[4][16][72];  // per-wave P staging

    const int n = blockIdx.y;
    const int qb = blockIdx.x;
    const int sp = blockIdx.z;
    const int q0 = qb * 64;
    const int key_base = sp * KPS;
    const int tid = threadIdx.x;
    const int w = tid >> 6, l = tid & 63;
    const int lm = l & 15, lk = (l >> 4) * 8;
    const int rbase = (l >> 4) * 4;

    const short* qh = q + (size_t)n * LTOK * HD;
    const short* kh = k + (size_t)n * LTOK * HD;
    const short* vh = vT + (size_t)n * HD * LTOK;

    bf16x8 qf[2];
    #pragma unroll
    for (int kk = 0; kk < 2; ++kk)
        qf[kk] = *(const bf16x8*)&qh[(size_t)(q0 + w * 16 + lm) * HD + kk * 32 + lk];

    for (int t = tid; t < 64 * 12; t += 256) {
        int row = t / 12, c4 = (t % 12) * 4;
        size_t rb = ((size_t)n * LTOK + q0 + row) * WG + c4;
        float4 hv = *(const float4*)&rel_h[rb];
        float4 wv = *(const float4*)&rel_w[rb];
        short4 hs, wsv;
        hs.x = f2b(hv.x); hs.y = f2b(hv.y); hs.z = f2b(hv.z); hs.w = f2b(hv.w);
        wsv.x = f2b(wv.x); wsv.y = f2b(wv.y); wsv.z = f2b(wv.z); wsv.w = f2b(wv.w);
        *(short4*)&rhb[row][c4] = hs;
        *(short4*)&rwb[row][c4] = wsv;
    }

    float m0[4], lsum[4];
    f32x4 oacc[4];
    const f32x4 zf = {0.f, 0.f, 0.f, 0.f};
    #pragma unroll
    for (int r = 0; r < 4; ++r) { m0[r] = -1e30f; lsum[r] = 0.f; }
    #pragma unroll
    for (int d = 0; d < 4; ++d) oacc[d] = zf;

    for (int kt = 0; kt < KPS / 64; ++kt) {
        const int key0 = key_base + kt * 64;
        __syncthreads();
        #pragma unroll
        for (int p = 0; p < 2; ++p) {
            int flat = tid + p * 256;
            int row = flat >> 3, colb = (flat & 7) * 8;
            *(bf16x8*)&ks[row][colb] = *(const bf16x8*)&kh[(size_t)(key0 + row) * HD + colb];
            *(bf16x8*)&vs[row][colb] = *(const bf16x8*)&vh[(size_t)row * LTOK + key0 + colb];
        }
        __syncthreads();

        f32x4 sf[4];
        #pragma unroll
        for (int f = 0; f < 4; ++f) {
            sf[f] = zf;
            #pragma unroll
            for (int kk = 0; kk < 2; ++kk) {
                bf16x8 kf = *(const bf16x8*)&ks[f * 16 + lm][kk * 32 + lk];
                sf[f] = __builtin_amdgcn_mfma_f32_16x16x32_bf16(qf[kk], kf, sf[f], 0, 0, 0);
            }
        }
        #pragma unroll
        for (int f = 0; f < 4; ++f) {
            int key = key0 + f * 16 + lm;
            int khi = key / WG, kwi = key - khi * WG;
            #pragma unroll
            for (int r = 0; r < 4; ++r)
                sf[f][r] = sf[f][r] * SCALE + b2f(rhb[w * 16 + rbase + r][khi])
                                            + b2f(rwb[w * 16 + rbase + r][kwi]);
        }
        float fac[4], rsum[4];
        #pragma unroll
        for (int r = 0; r < 4; ++r) {
            float mx = fmaxf(fmaxf(sf[0][r], sf[1][r]), fmaxf(sf[2][r], sf[3][r]));
            mx = fmaxf(mx, __shfl_xor(mx, 1));
            mx = fmaxf(mx, __shfl_xor(mx, 2));
            mx = fmaxf(mx, __shfl_xor(mx, 4));
            mx = fmaxf(mx, __shfl_xor(mx, 8));
            float mnew = fmaxf(m0[r], mx);
            fac[r] = __expf(m0[r] - mnew);
            m0[r] = mnew;
            rsum[r] = 0.f;
        }
        #pragma unroll
        for (int f = 0; f < 4; ++f)
            #pragma unroll
            for (int r = 0; r < 4; ++r) {
                float p = __expf(sf[f][r] - m0[r]);
                rsum[r] += p;
                ps[w][rbase + r][f * 16 + lm] = f2b(p);
            }
        #pragma unroll
        for (int r = 0; r < 4; ++r) {
            float s = rsum[r];
            s += __shfl_xor(s, 1); s += __shfl_xor(s, 2);
            s += __shfl_xor(s, 4); s += __shfl_xor(s, 8);
            lsum[r] = lsum[r] * fac[r] + s;
        }
        #pragma unroll
        for (int d = 0; d < 4; ++d)
            #pragma unroll
            for (int r = 0; r < 4; ++r)
                oacc[d][r] *= fac[r];
        #pragma unroll
        for (int kk = 0; kk < 2; ++kk) {
            bf16x8 pf = *(const bf16x8*)&ps[w][lm][kk * 32 + lk];
            #pragma unroll
            for (int d = 0; d < 4; ++d) {
                bf16x8 vf = *(const bf16x8*)&vs[d * 16 + lm][kk * 32 + lk];
                oacc[d] = __builtin_amdgcn_mfma_f32_16x16x32_bf16(pf, vf, oacc[d], 0, 0, 0);
            }
        }
    }

    // write unnormalized partials (f32) + per-row (m, l)
    size_t pbase = (((size_t)n * NQB + qb) * NSPLIT + sp) * 4096;
    #pragma unroll
    for (int d = 0; d < 4; ++d)
        #pragma unroll
        for (int r = 0; r < 4; ++r)
            o_part[pbase + (size_t)(w * 16 + rbase + r) * 64 + d * 16 + lm] = oacc[d][r];
    if (lm == 0) {
        size_t mlb = ((((size_t)n * NQB + qb) * NSPLIT + sp) * 64);
        #pragma unroll
        for (int r = 0; r < 4; ++r) {
            ml[(mlb + w * 16 + rbase + r) * 2]     = m0[r];
            ml[(mlb + w * 16 + rbase + r) * 2 + 1] = lsum[r];
        }
    }
}

// --------------------------- split-K combine -------------------------------
__global__ __launch_bounds__(256) void combine_kernel(
    const float* __restrict__ o_part, const float* __restrict__ ml,
    short* __restrict__ o)
{
    const int qb = blockIdx.x, h = blockIdx.y;
    const int t = threadIdx.x;
    const int row = t >> 2, dg = (t & 3) * 16;
    size_t pbase = (((size_t)h * NQB + qb) * NSPLIT) * 4096 + (size_t)row * 64 + dg;
    size_t mlb = (((size_t)h * NQB + qb) * NSPLIT) * 64 + row;
    float ma = ml[mlb * 2],        la = ml[mlb * 2 + 1];
    float mb = ml[(mlb + 64) * 2], lb = ml[(mlb + 64) * 2 + 1];
    float mc = ml[(mlb + 128) * 2], lc = ml[(mlb + 128) * 2 + 1];
    float M = fmaxf(ma, fmaxf(mb, mc));
    float wa = __expf(ma - M), wb = __expf(mb - M), wc = __expf(mc - M);
    float inv = 1.0f / (la * wa + lb * wb + lc * wc);
    float acc[16];
    #pragma unroll
    for (int c = 0; c < 16; c += 4) {
        float4 a = *(const float4*)&o_part[pbase + c];
        float4 b = *(const float4*)&o_part[pbase + 4096 + c];
        float4 g = *(const float4*)&o_part[pbase + 8192 + c];
        acc[c + 0] = (a.x * wa + b.x * wb + g.x * wc) * inv;
        acc[c + 1] = (a.y * wa + b.y * wb + g.y * wc) * inv;
        acc[c + 2] = (a.z * wa + b.z * wb + g.z * wc) * inv;
        acc[c + 3] = (a.w * wa + b.w * wb + g.w * wc) * inv;
    }
    bf16x8 o0, o1;
    #pragma unroll
    for (int j = 0; j < 8; ++j) { o0[j] = f2b(acc[j]); o1[j] = f2b(acc[8 + j]); }
    size_t ob = ((size_t)(qb * 64 + row)) * DIMC + h * 64 + dg;
    *(bf16x8*)&o[ob]     = o0;
    *(bf16x8*)&o[ob + 8] = o1;
}

// ---------------------------------------------------------------------------
extern "C" void kernel_launch(void* const* d_in, const int* in_sizes, int n_in,
                              void* d_out, int out_size, void* d_ws, size_t ws_size,
                              hipStream_t stream) {
    (void)in_sizes; (void)n_in; (void)out_size; (void)ws_size;
    const float* x         = (const float*)d_in[0];
    const float* w_qkv     = (const float*)d_in[1];
    const float* b_qkv     = (const float*)d_in[2];
    const float* w_proj    = (const float*)d_in[3];
    const float* b_proj    = (const float*)d_in[4];
    const float* rel_pos_h = (const float*)d_in[5];
    const float* rel_pos_w = (const float*)d_in[6];
    float* out = (float*)d_out;

    float* qkv_raw = (float*)d_ws;                         // L*2304 f32 (dead after split_rope)
    float* o_part  = qkv_raw;                              // alias: 12*36*3*4096 f32 == same size
    float* rel_h   = qkv_raw + (size_t)LTOK * QKVN;
    float* rel_w   = rel_h + (size_t)NH * LTOK * WG;
    float* cost    = rel_w + (size_t)NH * LTOK * WG;
    float* sint    = cost + (size_t)LTOK * 32;
    short* xb      = (short*)(sint + (size_t)LTOK * 32);
    short* wqkvT   = xb + (size_t)LTOK * DIMC;
    short* wprojT  = wqkvT + (size_t)QKVN * DIMC;
    short* qb      = wprojT + (size_t)DIMC * DIMC;
    short* kb      = qb + (size_t)NH * LTOK * HD;
    short* vTb     = kb + (size_t)NH * LTOK * HD;
    short* ob      = vTb + (size_t)NH * LTOK * HD;
    float* ml      = (float*)(ob + (size_t)LTOK * DIMC);   // 12*36*3*64*2 f32

    rope_table_kernel<<<(LTOK * 32 + 255) / 256, 256, 0, stream>>>(cost, sint);

    cast_bf16_kernel<<<(LTOK * DIMC / 8 + 255) / 256, 256, 0, stream>>>(
        x, xb, LTOK * DIMC / 8);
    transpose_cast_kernel<<<dim3(QKVN / 32, DIMC / 32), 256, 0, stream>>>(
        w_qkv, wqkvT, DIMC, QKVN);
    transpose_cast_kernel<<<dim3(DIMC / 32, DIMC / 32), 256, 0, stream>>>(
        w_proj, wprojT, DIMC, DIMC);

    gemm_bf16_kernel<<<dim3(QKVN / 128, LTOK / 128), 256, 0, stream>>>(
        xb, wqkvT, b_qkv, qkv_raw, LTOK, QKVN, DIMC);

    split_rope_kernel<<<dim3(LTOK / 64, NH), 256, 0, stream>>>(
        qkv_raw, cost, sint, qb, kb, vTb);

    relbias_kernel<<<dim3(LTOK / 16, NH), 256, 0, stream>>>(
        qb, rel_pos_h, rel_pos_w, rel_h, rel_w);

    attn_kernel<<<dim3(NQB, NH, NSPLIT), 256, 0, stream>>>(
        qb, kb, vTb, rel_h, rel_w, o_part, ml);

    combine_kernel<<<dim3(NQB, NH), 256, 0, stream>>>(o_part, ml, ob);

    gemm_bf16_kernel<<<dim3(DIMC / 128, LTOK / 128), 256, 0, stream>>>(
        ob, wprojT, b_proj, out, LTOK, DIMC, DIMC);
}

// Round 4
// 159.366 us; speedup vs baseline: 7.0591x; 1.1526x over previous
//
#include <hip/hip_runtime.h>
#include <hip/hip_bf16.h>

// ---------------------------------------------------------------------------
// TRTAttention round 4: bias folded into MFMA via one-hot K_ext (dim 160),
// fixed m=0 softmax (no max tracking), T14 async-stage split in attn.
// L=2304 (48x48), dim=768, 12 heads x 64. bf16 MFMA, fp32 accumulate.
// ---------------------------------------------------------------------------

typedef short bf16x8 __attribute__((ext_vector_type(8)));
typedef float f32x4  __attribute__((ext_vector_type(4)));

namespace {
constexpr int LTOK = 2304;
constexpr int DIMC = 768;
constexpr int NH   = 12;
constexpr int HD   = 64;
constexpr int WG   = 48;
constexpr int QKVN = 2304;
constexpr int EXT  = 160;             // 64 + 48 + 48 augmented head dim
constexpr int NSPLIT = 3;
constexpr int KPS  = LTOK / NSPLIT;   // 768 keys per split
constexpr int NT   = KPS / 64;        // 12 key tiles per split
constexpr int NQB  = LTOK / 64;       // 36 q-blocks
constexpr float SCALE = 0.125f;
}

__device__ __forceinline__ short f2b(float f) {
    __hip_bfloat16 h = __float2bfloat16(f);
    return *reinterpret_cast<short*>(&h);
}
__device__ __forceinline__ float b2f(short s) {
    return __uint_as_float(((unsigned)(unsigned short)s) << 16);
}
__device__ __forceinline__ void load16_to_lds(const short* g, short* l) {
    __builtin_amdgcn_global_load_lds(
        (__attribute__((address_space(1))) void*)g,
        (__attribute__((address_space(3))) void*)l,
        16, 0, 0);
}

// --------------------------- rope tables -----------------------------------
__global__ void rope_table_kernel(float* __restrict__ cost, float* __restrict__ sint) {
    int idx = blockIdx.x * blockDim.x + threadIdx.x;
    if (idx >= LTOK * 32) return;
    int j = idx & 31;
    int l = idx >> 5;
    float t = (j < 16) ? (float)(l % WG) : (float)(l / WG);
    int fi = j & 15;
    float freq = powf(10000.0f, -(float)fi / 16.0f);
    float ang = t * freq;
    cost[idx] = cosf(ang);
    sint[idx] = sinf(ang);
}

// --------------------------- fp32 -> bf16 cast -----------------------------
__global__ void cast_bf16_kernel(const float* __restrict__ in, short* __restrict__ out, int n8) {
    int i = blockIdx.x * blockDim.x + threadIdx.x;
    if (i >= n8) return;
    float4 a = ((const float4*)in)[2 * i];
    float4 b = ((const float4*)in)[2 * i + 1];
    bf16x8 o;
    o[0] = f2b(a.x); o[1] = f2b(a.y); o[2] = f2b(a.z); o[3] = f2b(a.w);
    o[4] = f2b(b.x); o[5] = f2b(b.y); o[6] = f2b(b.z); o[7] = f2b(b.w);
    ((bf16x8*)out)[i] = o;
}

// ----------------- fp32 (R,C) -> bf16 (C,R) transpose+cast -----------------
__global__ __launch_bounds__(256) void transpose_cast_kernel(
    const float* __restrict__ in, short* __restrict__ out, int R, int C) {
    __shared__ float ts[32][36];
    const int c0 = blockIdx.x * 32, r0 = blockIdx.y * 32;
    const int t = threadIdx.x;
    {
        int r = t >> 3, cb = (t & 7) * 4;
        float4 v = *(const float4*)&in[(size_t)(r0 + r) * C + c0 + cb];
        ts[r][cb] = v.x; ts[r][cb + 1] = v.y; ts[r][cb + 2] = v.z; ts[r][cb + 3] = v.w;
    }
    __syncthreads();
    {
        int oc = t >> 3, rb = (t & 7) * 4;
        short4 s;
        s.x = f2b(ts[rb][oc]);     s.y = f2b(ts[rb + 1][oc]);
        s.z = f2b(ts[rb + 2][oc]); s.w = f2b(ts[rb + 3][oc]);
        *(short4*)&out[(size_t)(c0 + oc) * R + r0 + rb] = s;
    }
}

// --------------------------- bf16 MFMA GEMM (m97-style) --------------------
__global__ __launch_bounds__(256) void gemm_bf16_kernel(
    const short* __restrict__ A, const short* __restrict__ Bt,
    const float* __restrict__ bias, float* __restrict__ C,
    int M, int N, int K)
{
    __shared__ short As[128 * 64];
    __shared__ short Bs[128 * 64];
    const int tid = threadIdx.x;
    const int bm = blockIdx.y * 128, bn = blockIdx.x * 128;
    const int w = tid >> 6, l = tid & 63;
    const int wr = w >> 1, wc = w & 1;
    const int lm = l & 15, lk = (l >> 4) * 8;

    f32x4 acc[4][4];
    const f32x4 zf = {0.f, 0.f, 0.f, 0.f};
    #pragma unroll
    for (int m = 0; m < 4; ++m)
        #pragma unroll
        for (int n = 0; n < 4; ++n) acc[m][n] = zf;

    for (int k0 = 0; k0 < K; k0 += 64) {
        __syncthreads();
        #pragma unroll
        for (int p = 0; p < 4; ++p) {
            int f = tid + p * 256;
            int row = f >> 3, c8 = (f & 7) * 8;
            load16_to_lds(&A[(size_t)(bm + row) * K + k0 + c8], &As[f * 8]);
            load16_to_lds(&Bt[(size_t)(bn + row) * K + k0 + c8], &Bs[f * 8]);
        }
        __syncthreads();
        #pragma unroll
        for (int kh = 0; kh < 2; ++kh) {
            bf16x8 a[4], b[4];
            #pragma unroll
            for (int m = 0; m < 4; ++m)
                a[m] = *(const bf16x8*)&As[(wr * 64 + m * 16 + lm) * 64 + kh * 32 + lk];
            #pragma unroll
            for (int n = 0; n < 4; ++n)
                b[n] = *(const bf16x8*)&Bs[(wc * 64 + n * 16 + lm) * 64 + kh * 32 + lk];
            #pragma unroll
            for (int m = 0; m < 4; ++m)
                #pragma unroll
                for (int n = 0; n < 4; ++n)
                    acc[m][n] = __builtin_amdgcn_mfma_f32_16x16x32_bf16(a[m], b[n], acc[m][n], 0, 0, 0);
        }
    }
    const int orow = (l >> 4) * 4;
    #pragma unroll
    for (int m = 0; m < 4; ++m) {
        #pragma unroll
        for (int n = 0; n < 4; ++n) {
            int col = bn + wc * 64 + n * 16 + lm;
            float bv = bias[col];
            #pragma unroll
            for (int r = 0; r < 4; ++r) {
                int row = bm + wr * 64 + m * 16 + orow + r;
                C[(size_t)row * N + col] = acc[m][n][r] + bv;
            }
        }
    }
}

// ------ split qkv + rope -> qb (unscaled), q_ext (scaled), k_ext, vT -------
// grid (L/64, NH), 256 thr.
__global__ __launch_bounds__(256) void split_rope_kernel(
    const float* __restrict__ qkv_raw,
    const float* __restrict__ cost, const float* __restrict__ sint,
    short* __restrict__ qb, short* __restrict__ q_ext,
    short* __restrict__ k_ext, short* __restrict__ vT)
{
    __shared__ short vt_s[64][72];
    const int h = blockIdx.y;
    const int l0 = blockIdx.x * 64;
    const int t = threadIdx.x;
    const int tok = t >> 2, dq = (t & 3) * 16;
    const int l = l0 + tok;
    const float* row = qkv_raw + (size_t)l * QKVN + h * HD;

    bf16x8 qv[2], qe[2], kv[2];
    #pragma unroll
    for (int i = 0; i < 16; i += 4) {
        int d = dq + i;
        float4 tq = *(const float4*)&row[d];
        float4 tk = *(const float4*)&row[DIMC + d];
        float4 tv = *(const float4*)&row[2 * DIMC + d];
        float2 c01 = *(const float2*)&cost[l * 32 + d / 2];
        float2 s01 = *(const float2*)&sint[l * 32 + d / 2];
        float q0 = tq.x * c01.x - tq.y * s01.x;
        float q1 = tq.x * s01.x + tq.y * c01.x;
        float q2 = tq.z * c01.y - tq.w * s01.y;
        float q3 = tq.z * s01.y + tq.w * c01.y;
        qv[i >> 3][(i & 7) + 0] = f2b(q0);
        qv[i >> 3][(i & 7) + 1] = f2b(q1);
        qv[i >> 3][(i & 7) + 2] = f2b(q2);
        qv[i >> 3][(i & 7) + 3] = f2b(q3);
        qe[i >> 3][(i & 7) + 0] = f2b(q0 * SCALE);
        qe[i >> 3][(i & 7) + 1] = f2b(q1 * SCALE);
        qe[i >> 3][(i & 7) + 2] = f2b(q2 * SCALE);
        qe[i >> 3][(i & 7) + 3] = f2b(q3 * SCALE);
        kv[i >> 3][(i & 7) + 0] = f2b(tk.x * c01.x - tk.y * s01.x);
        kv[i >> 3][(i & 7) + 1] = f2b(tk.x * s01.x + tk.y * c01.x);
        kv[i >> 3][(i & 7) + 2] = f2b(tk.z * c01.y - tk.w * s01.y);
        kv[i >> 3][(i & 7) + 3] = f2b(tk.z * s01.y + tk.w * c01.y);
        vt_s[d + 0][tok] = f2b(tv.x);
        vt_s[d + 1][tok] = f2b(tv.y);
        vt_s[d + 2][tok] = f2b(tv.z);
        vt_s[d + 3][tok] = f2b(tv.w);
    }
    size_t qbase = ((size_t)h * LTOK + l) * HD + dq;
    *(bf16x8*)&qb[qbase]     = qv[0];
    *(bf16x8*)&qb[qbase + 8] = qv[1];
    size_t ebase = ((size_t)h * LTOK + l) * EXT + dq;
    *(bf16x8*)&q_ext[ebase]     = qe[0];
    *(bf16x8*)&q_ext[ebase + 8] = qe[1];
    *(bf16x8*)&k_ext[ebase]     = kv[0];
    *(bf16x8*)&k_ext[ebase + 8] = kv[1];
    // one-hot region of k_ext: cols 64..159; 1.0 at 64+khi and 112+kwi
    for (int i = t; i < 64 * 12; i += 256) {
        int key = l0 + i / 12;
        int seg = i % 12;
        int khi = key / WG, kwi = key - khi * WG;
        const short one = f2b(1.0f);
        bf16x8 oh;
        #pragma unroll
        for (int j = 0; j < 8; ++j) {
            int col = 64 + seg * 8 + j;
            oh[j] = (col == 64 + khi || col == 112 + kwi) ? one : (short)0;
        }
        *(bf16x8*)&k_ext[((size_t)h * LTOK + key) * EXT + 64 + seg * 8] = oh;
    }
    __syncthreads();
    const int drow = t >> 2, lq = (t & 3) * 16;
    bf16x8 v0 = *(bf16x8*)&vt_s[drow][lq];
    bf16x8 v1 = *(bf16x8*)&vt_s[drow][lq + 8];
    size_t vbase = ((size_t)h * HD + drow) * LTOK + l0 + lq;
    *(bf16x8*)&vT[vbase]     = v0;
    *(bf16x8*)&vT[vbase + 8] = v1;
}

// ----------------- decomposed rel-pos bias -> q_ext cols 64..159 -----------
__global__ __launch_bounds__(256) void relbias_kernel(
    const short* __restrict__ qb,
    const float* __restrict__ rel_pos_h, const float* __restrict__ rel_pos_w,
    short* __restrict__ q_ext)
{
    __shared__ float qs2[16][68];
    __shared__ float rph_s[48][68];
    __shared__ float rpw_s[63][68];
    const int nb = blockIdx.y;
    const int l0 = blockIdx.x * 16;
    const int h0 = l0 / WG, w0 = l0 % WG;
    const int t = threadIdx.x;
    {
        int flat = t * 4;
        int row = flat >> 6, col = flat & 63;
        const short* src = &qb[((size_t)nb * LTOK + l0 + row) * HD + col];
        qs2[row][col] = b2f(src[0]); qs2[row][col + 1] = b2f(src[1]);
        qs2[row][col + 2] = b2f(src[2]); qs2[row][col + 3] = b2f(src[3]);
    }
    for (int i = t; i < (48 + 63) * 16; i += 256) {
        int rr = i >> 4, c4 = (i & 15) * 4;
        if (rr < 48)
            *(float4*)&rph_s[rr][c4] = *(const float4*)&rel_pos_h[(size_t)(h0 + rr) * HD + c4];
        else
            *(float4*)&rpw_s[rr - 48][c4] = *(const float4*)&rel_pos_w[(size_t)(w0 + rr - 48) * HD + c4];
    }
    __syncthreads();
    const int ti = t >> 4, kg = t & 15;
    for (int ko = kg; ko < 96; ko += 16) {
        bool ish = ko < 48;
        int kk = ish ? ko : ko - 48;
        const float* br = ish ? &rph_s[47 - kk][0] : &rpw_s[ti + 47 - kk][0];
        float s = 0.f;
        #pragma unroll
        for (int c = 0; c < HD; c += 4) {
            float4 a = *(const float4*)&qs2[ti][c];
            float4 b = *(const float4*)&br[c];
            s += a.x * b.x + a.y * b.y + a.z * b.z + a.w * b.w;
        }
        int col = ish ? (64 + kk) : (112 + kk);
        q_ext[((size_t)nb * LTOK + l0 + ti) * EXT + col] = f2b(s);
    }
}

// --------------------------- split-K flash attention -----------------------
// grid (36, 12, 3); 4 waves; wave w owns q-rows [w*16, w*16+16).
// S = Q_ext . K_ext^T (bias folded in); fixed m=0 softmax; T14 async stage.
__global__ __launch_bounds__(256, 4) void attn_kernel(
    const short* __restrict__ q_ext, const short* __restrict__ k_ext,
    const short* __restrict__ vT, float* __restrict__ o_part,
    float* __restrict__ lsum_g)
{
    __shared__ short ks[64][168];    // [key][ext-dim], pad 168 for 2-way reads
    __shared__ short vs[64][72];     // [d][key]
    __shared__ short ps[4][16][72];  // per-wave P staging

    const int n = blockIdx.y;
    const int qb = blockIdx.x;
    const int sp = blockIdx.z;
    const int q0 = qb * 64;
    const int key_base = sp * KPS;
    const int tid = threadIdx.x;
    const int w = tid >> 6, l = tid & 63;
    const int lm = l & 15, lk = (l >> 4) * 8;
    const int rbase = (l >> 4) * 4;

    const short* qeh = q_ext + (size_t)n * LTOK * EXT;
    const short* keh = k_ext + (size_t)n * LTOK * EXT;
    const short* vh  = vT + (size_t)n * HD * LTOK;

    // Q_ext fragments: 5 x bf16x8 covering 160 dims, resident in regs
    bf16x8 qf[5];
    #pragma unroll
    for (int kk = 0; kk < 5; ++kk)
        qf[kk] = *(const bf16x8*)&qeh[(size_t)(q0 + w * 16 + lm) * EXT + kk * 32 + lk];

    // staging registers (T14 split: issue early, write late)
    bf16x8 kreg[5], vreg[2];
    const int krow = (tid * 5) / 20 < 0 ? 0 : 0; (void)krow; // (no-op; keep indices below)

    #define ISSUE_LOADS(kt_)  do {                                            \
        const int key0_ = key_base + (kt_) * 64;                              \
        _Pragma("unroll")                                                     \
        for (int p = 0; p < 5; ++p) {                                         \
            int f_ = tid + p * 256;                                           \
            int row_ = f_ / 20, c8_ = (f_ % 20) * 8;                          \
            kreg[p] = *(const bf16x8*)&keh[(size_t)(key0_ + row_) * EXT + c8_]; \
        }                                                                     \
        _Pragma("unroll")                                                     \
        for (int p = 0; p < 2; ++p) {                                         \
            int f_ = tid + p * 256;                                           \
            int row_ = f_ >> 3, c8_ = (f_ & 7) * 8;                           \
            vreg[p] = *(const bf16x8*)&vh[(size_t)row_ * LTOK + key0_ + c8_]; \
        }                                                                     \
    } while (0)

    float lsum[4];
    f32x4 oacc[4];
    const f32x4 zf = {0.f, 0.f, 0.f, 0.f};
    #pragma unroll
    for (int r = 0; r < 4; ++r) lsum[r] = 0.f;
    #pragma unroll
    for (int d = 0; d < 4; ++d) oacc[d] = zf;

    ISSUE_LOADS(0);

    for (int kt = 0; kt < NT; ++kt) {
        __syncthreads();   // all waves done reading LDS tile kt-1
        // write staged regs -> LDS (compiler inserts vmcnt waits)
        #pragma unroll
        for (int p = 0; p < 5; ++p) {
            int f = tid + p * 256;
            int row = f / 20, c8 = (f % 20) * 8;
            *(bf16x8*)&ks[row][c8] = kreg[p];
        }
        #pragma unroll
        for (int p = 0; p < 2; ++p) {
            int f = tid + p * 256;
            int row = f >> 3, c8 = (f & 7) * 8;
            *(bf16x8*)&vs[row][c8] = vreg[p];
        }
        if (kt + 1 < NT) { ISSUE_LOADS(kt + 1); }
        __builtin_amdgcn_sched_barrier(0);   // pin loads before compute
        __syncthreads();   // LDS tile kt ready

        // S = Q_ext . K_ext^T : 16 q-rows x 64 keys per wave, K-dim 160
        f32x4 sf[4];
        #pragma unroll
        for (int f = 0; f < 4; ++f) {
            sf[f] = zf;
            #pragma unroll
            for (int kk = 0; kk < 5; ++kk) {
                bf16x8 kf = *(const bf16x8*)&ks[f * 16 + lm][kk * 32 + lk];
                sf[f] = __builtin_amdgcn_mfma_f32_16x16x32_bf16(qf[kk], kf, sf[f], 0, 0, 0);
            }
        }
        // fixed-max softmax: p = exp(s), no rescale
        float rsum[4] = {0.f, 0.f, 0.f, 0.f};
        #pragma unroll
        for (int f = 0; f < 4; ++f)
            #pragma unroll
            for (int r = 0; r < 4; ++r) {
                float p = __expf(sf[f][r]);
                rsum[r] += p;
                ps[w][rbase + r][f * 16 + lm] = f2b(p);
            }
        #pragma unroll
        for (int r = 0; r < 4; ++r) {
            float s = rsum[r];
            s += __shfl_xor(s, 1); s += __shfl_xor(s, 2);
            s += __shfl_xor(s, 4); s += __shfl_xor(s, 8);
            lsum[r] += s;
        }
        // PV: O += P @ V
        #pragma unroll
        for (int kk = 0; kk < 2; ++kk) {
            bf16x8 pf = *(const bf16x8*)&ps[w][lm][kk * 32 + lk];
            #pragma unroll
            for (int d = 0; d < 4; ++d) {
                bf16x8 vf = *(const bf16x8*)&vs[d * 16 + lm][kk * 32 + lk];
                oacc[d] = __builtin_amdgcn_mfma_f32_16x16x32_bf16(pf, vf, oacc[d], 0, 0, 0);
            }
        }
    }
    #undef ISSUE_LOADS

    // write unnormalized partials + per-row partial denominators
    size_t pbase = (((size_t)n * NQB + qb) * NSPLIT + sp) * 4096;
    #pragma unroll
    for (int d = 0; d < 4; ++d)
        #pragma unroll
        for (int r = 0; r < 4; ++r)
            o_part[pbase + (size_t)(w * 16 + rbase + r) * 64 + d * 16 + lm] = oacc[d][r];
    if (lm == 0) {
        size_t lb = (((size_t)n * NQB + qb) * NSPLIT + sp) * 64;
        #pragma unroll
        for (int r = 0; r < 4; ++r)
            lsum_g[lb + w * 16 + rbase + r] = lsum[r];
    }
}

// --------------------------- split-K combine -------------------------------
__global__ __launch_bounds__(256) void combine_kernel(
    const float* __restrict__ o_part, const float* __restrict__ lsum_g,
    short* __restrict__ o)
{
    const int qb = blockIdx.x, h = blockIdx.y;
    const int t = threadIdx.x;
    const int row = t >> 2, dg = (t & 3) * 16;
    size_t pbase = (((size_t)h * NQB + qb) * NSPLIT) * 4096 + (size_t)row * 64 + dg;
    size_t lb = (((size_t)h * NQB + qb) * NSPLIT) * 64 + row;
    float la = lsum_g[lb], lbv = lsum_g[lb + 64], lc = lsum_g[lb + 128];
    float inv = 1.0f / (la + lbv + lc);
    float acc[16];
    #pragma unroll
    for (int c = 0; c < 16; c += 4) {
        float4 a = *(const float4*)&o_part[pbase + c];
        float4 b = *(const float4*)&o_part[pbase + 4096 + c];
        float4 g = *(const float4*)&o_part[pbase + 8192 + c];
        acc[c + 0] = (a.x + b.x + g.x) * inv;
        acc[c + 1] = (a.y + b.y + g.y) * inv;
        acc[c + 2] = (a.z + b.z + g.z) * inv;
        acc[c + 3] = (a.w + b.w + g.w) * inv;
    }
    bf16x8 o0, o1;
    #pragma unroll
    for (int j = 0; j < 8; ++j) { o0[j] = f2b(acc[j]); o1[j] = f2b(acc[8 + j]); }
    size_t ob = ((size_t)(qb * 64 + row)) * DIMC + h * 64 + dg;
    *(bf16x8*)&o[ob]     = o0;
    *(bf16x8*)&o[ob + 8] = o1;
}

// ---------------------------------------------------------------------------
extern "C" void kernel_launch(void* const* d_in, const int* in_sizes, int n_in,
                              void* d_out, int out_size, void* d_ws, size_t ws_size,
                              hipStream_t stream) {
    (void)in_sizes; (void)n_in; (void)out_size; (void)ws_size;
    const float* x         = (const float*)d_in[0];
    const float* w_qkv     = (const float*)d_in[1];
    const float* b_qkv     = (const float*)d_in[2];
    const float* w_proj    = (const float*)d_in[3];
    const float* b_proj    = (const float*)d_in[4];
    const float* rel_pos_h = (const float*)d_in[5];
    const float* rel_pos_w = (const float*)d_in[6];
    float* out = (float*)d_out;

    float* qkv_raw = (float*)d_ws;                         // 5.31M f32 (dead after split_rope)
    float* o_part  = qkv_raw;                              // alias: 12*36*3*4096 f32, same size
    float* cost    = qkv_raw + (size_t)LTOK * QKVN;
    float* sint    = cost + (size_t)LTOK * 32;
    float* lsum_g  = sint + (size_t)LTOK * 32;             // 12*36*3*64 f32
    short* xb      = (short*)(lsum_g + (size_t)NH * NQB * NSPLIT * 64);
    short* wqkvT   = xb + (size_t)LTOK * DIMC;
    short* wprojT  = wqkvT + (size_t)QKVN * DIMC;
    short* qb      = wprojT + (size_t)DIMC * DIMC;         // unscaled rotated q
    short* q_ext   = qb + (size_t)NH * LTOK * HD;          // [h][l][160]
    short* k_ext   = q_ext + (size_t)NH * LTOK * EXT;      // [h][key][160]
    short* vTb     = k_ext + (size_t)NH * LTOK * EXT;      // [h][d][L]
    short* ob      = vTb + (size_t)NH * LTOK * HD;         // L*768
    // total ~59 MB of d_ws

    rope_table_kernel<<<(LTOK * 32 + 255) / 256, 256, 0, stream>>>(cost, sint);

    cast_bf16_kernel<<<(LTOK * DIMC / 8 + 255) / 256, 256, 0, stream>>>(
        x, xb, LTOK * DIMC / 8);
    transpose_cast_kernel<<<dim3(QKVN / 32, DIMC / 32), 256, 0, stream>>>(
        w_qkv, wqkvT, DIMC, QKVN);
    transpose_cast_kernel<<<dim3(DIMC / 32, DIMC / 32), 256, 0, stream>>>(
        w_proj, wprojT, DIMC, DIMC);

    gemm_bf16_kernel<<<dim3(QKVN / 128, LTOK / 128), 256, 0, stream>>>(
        xb, wqkvT, b_qkv, qkv_raw, LTOK, QKVN, DIMC);

    split_rope_kernel<<<dim3(LTOK / 64, NH), 256, 0, stream>>>(
        qkv_raw, cost, sint, qb, q_ext, k_ext, vTb);

    relbias_kernel<<<dim3(LTOK / 16, NH), 256, 0, stream>>>(
        qb, rel_pos_h, rel_pos_w, q_ext);

    attn_kernel<<<dim3(NQB, NH, NSPLIT), 256, 0, stream>>>(
        q_ext, k_ext, vTb, o_part, lsum_g);

    combine_kernel<<<dim3(NQB, NH), 256, 0, stream>>>(o_part, lsum_g, ob);

    gemm_bf16_kernel<<<dim3(DIMC / 128, LTOK / 128), 256, 0, stream>>>(
        ob, wprojT, b_proj, out, LTOK, DIMC, DIMC);
}

// Round 5
// 148.870 us; speedup vs baseline: 7.5568x; 1.0705x over previous
//
#include <hip/hip_runtime.h>
#include <hip/hip_bf16.h>

// ---------------------------------------------------------------------------
// TRTAttention round 5: swapped-operand S MFMA + permuted-K staging so the PV
// A-fragment assembles IN-LANE (no P LDS round-trip, no shuffles); 32 q-rows
// per wave (halves ks LDS reads per output); 64x64-tile proj GEMM; staged
// vectorized relbias writes. bf16 MFMA, fp32 accumulate, fixed-max softmax.
// ---------------------------------------------------------------------------

typedef short bf16x8 __attribute__((ext_vector_type(8)));
typedef float f32x4  __attribute__((ext_vector_type(4)));

namespace {
constexpr int LTOK = 2304;
constexpr int DIMC = 768;
constexpr int NH   = 12;
constexpr int HD   = 64;
constexpr int WG   = 48;
constexpr int QKVN = 2304;
constexpr int EXT  = 160;             // 64 + 48 + 48 augmented head dim
constexpr int NSPLIT = 3;
constexpr int KPS  = LTOK / NSPLIT;   // 768 keys per split
constexpr int NT   = KPS / 64;        // 12 key tiles per split
constexpr int NQB2 = LTOK / 128;      // 18 q-blocks (128 rows each)
constexpr float SCALE = 0.125f;
}

__device__ __forceinline__ short f2b(float f) {
    __hip_bfloat16 h = __float2bfloat16(f);
    return *reinterpret_cast<short*>(&h);
}
__device__ __forceinline__ float b2f(short s) {
    return __uint_as_float(((unsigned)(unsigned short)s) << 16);
}
__device__ __forceinline__ void load16_to_lds(const short* g, short* l) {
    __builtin_amdgcn_global_load_lds(
        (__attribute__((address_space(1))) void*)g,
        (__attribute__((address_space(3))) void*)l,
        16, 0, 0);
}

// --------------------------- rope tables -----------------------------------
__global__ void rope_table_kernel(float* __restrict__ cost, float* __restrict__ sint) {
    int idx = blockIdx.x * blockDim.x + threadIdx.x;
    if (idx >= LTOK * 32) return;
    int j = idx & 31;
    int l = idx >> 5;
    float t = (j < 16) ? (float)(l % WG) : (float)(l / WG);
    int fi = j & 15;
    float freq = powf(10000.0f, -(float)fi / 16.0f);
    float ang = t * freq;
    cost[idx] = cosf(ang);
    sint[idx] = sinf(ang);
}

// --------------------------- fp32 -> bf16 cast -----------------------------
__global__ void cast_bf16_kernel(const float* __restrict__ in, short* __restrict__ out, int n8) {
    int i = blockIdx.x * blockDim.x + threadIdx.x;
    if (i >= n8) return;
    float4 a = ((const float4*)in)[2 * i];
    float4 b = ((const float4*)in)[2 * i + 1];
    bf16x8 o;
    o[0] = f2b(a.x); o[1] = f2b(a.y); o[2] = f2b(a.z); o[3] = f2b(a.w);
    o[4] = f2b(b.x); o[5] = f2b(b.y); o[6] = f2b(b.z); o[7] = f2b(b.w);
    ((bf16x8*)out)[i] = o;
}

// ----------------- fp32 (R,C) -> bf16 (C,R) transpose+cast -----------------
__global__ __launch_bounds__(256) void transpose_cast_kernel(
    const float* __restrict__ in, short* __restrict__ out, int R, int C) {
    __shared__ float ts[32][36];
    const int c0 = blockIdx.x * 32, r0 = blockIdx.y * 32;
    const int t = threadIdx.x;
    {
        int r = t >> 3, cb = (t & 7) * 4;
        float4 v = *(const float4*)&in[(size_t)(r0 + r) * C + c0 + cb];
        ts[r][cb] = v.x; ts[r][cb + 1] = v.y; ts[r][cb + 2] = v.z; ts[r][cb + 3] = v.w;
    }
    __syncthreads();
    {
        int oc = t >> 3, rb = (t & 7) * 4;
        short4 s;
        s.x = f2b(ts[rb][oc]);     s.y = f2b(ts[rb + 1][oc]);
        s.z = f2b(ts[rb + 2][oc]); s.w = f2b(ts[rb + 3][oc]);
        *(short4*)&out[(size_t)(c0 + oc) * R + r0 + rb] = s;
    }
}

// --------------------------- bf16 MFMA GEMM 128x128 ------------------------
__global__ __launch_bounds__(256) void gemm_bf16_kernel(
    const short* __restrict__ A, const short* __restrict__ Bt,
    const float* __restrict__ bias, float* __restrict__ C,
    int M, int N, int K)
{
    __shared__ short As[128 * 64];
    __shared__ short Bs[128 * 64];
    const int tid = threadIdx.x;
    const int bm = blockIdx.y * 128, bn = blockIdx.x * 128;
    const int w = tid >> 6, l = tid & 63;
    const int wr = w >> 1, wc = w & 1;
    const int lm = l & 15, lk = (l >> 4) * 8;

    f32x4 acc[4][4];
    const f32x4 zf = {0.f, 0.f, 0.f, 0.f};
    #pragma unroll
    for (int m = 0; m < 4; ++m)
        #pragma unroll
        for (int n = 0; n < 4; ++n) acc[m][n] = zf;

    for (int k0 = 0; k0 < K; k0 += 64) {
        __syncthreads();
        #pragma unroll
        for (int p = 0; p < 4; ++p) {
            int f = tid + p * 256;
            int row = f >> 3, c8 = (f & 7) * 8;
            load16_to_lds(&A[(size_t)(bm + row) * K + k0 + c8], &As[f * 8]);
            load16_to_lds(&Bt[(size_t)(bn + row) * K + k0 + c8], &Bs[f * 8]);
        }
        __syncthreads();
        #pragma unroll
        for (int kh = 0; kh < 2; ++kh) {
            bf16x8 a[4], b[4];
            #pragma unroll
            for (int m = 0; m < 4; ++m)
                a[m] = *(const bf16x8*)&As[(wr * 64 + m * 16 + lm) * 64 + kh * 32 + lk];
            #pragma unroll
            for (int n = 0; n < 4; ++n)
                b[n] = *(const bf16x8*)&Bs[(wc * 64 + n * 16 + lm) * 64 + kh * 32 + lk];
            #pragma unroll
            for (int m = 0; m < 4; ++m)
                #pragma unroll
                for (int n = 0; n < 4; ++n)
                    acc[m][n] = __builtin_amdgcn_mfma_f32_16x16x32_bf16(a[m], b[n], acc[m][n], 0, 0, 0);
        }
    }
    const int orow = (l >> 4) * 4;
    #pragma unroll
    for (int m = 0; m < 4; ++m) {
        #pragma unroll
        for (int n = 0; n < 4; ++n) {
            int col = bn + wc * 64 + n * 16 + lm;
            float bv = bias[col];
            #pragma unroll
            for (int r = 0; r < 4; ++r) {
                int row = bm + wr * 64 + m * 16 + orow + r;
                C[(size_t)row * N + col] = acc[m][n][r] + bv;
            }
        }
    }
}

// --------------------------- bf16 MFMA GEMM 64x64 (small-N) ----------------
__global__ __launch_bounds__(256) void gemm64_bf16_kernel(
    const short* __restrict__ A, const short* __restrict__ Bt,
    const float* __restrict__ bias, float* __restrict__ C,
    int M, int N, int K)
{
    __shared__ short As[64 * 64];
    __shared__ short Bs[64 * 64];
    const int tid = threadIdx.x;
    const int bm = blockIdx.y * 64, bn = blockIdx.x * 64;
    const int w = tid >> 6, l = tid & 63;
    const int wr = w >> 1, wc = w & 1;
    const int lm = l & 15, lk = (l >> 4) * 8;

    f32x4 acc[2][2];
    const f32x4 zf = {0.f, 0.f, 0.f, 0.f};
    acc[0][0] = zf; acc[0][1] = zf; acc[1][0] = zf; acc[1][1] = zf;

    for (int k0 = 0; k0 < K; k0 += 64) {
        __syncthreads();
        #pragma unroll
        for (int p = 0; p < 2; ++p) {
            int f = tid + p * 256;
            int row = f >> 3, c8 = (f & 7) * 8;
            load16_to_lds(&A[(size_t)(bm + row) * K + k0 + c8], &As[f * 8]);
            load16_to_lds(&Bt[(size_t)(bn + row) * K + k0 + c8], &Bs[f * 8]);
        }
        __syncthreads();
        #pragma unroll
        for (int kh = 0; kh < 2; ++kh) {
            bf16x8 a[2], b[2];
            #pragma unroll
            for (int m = 0; m < 2; ++m)
                a[m] = *(const bf16x8*)&As[(wr * 32 + m * 16 + lm) * 64 + kh * 32 + lk];
            #pragma unroll
            for (int n = 0; n < 2; ++n)
                b[n] = *(const bf16x8*)&Bs[(wc * 32 + n * 16 + lm) * 64 + kh * 32 + lk];
            #pragma unroll
            for (int m = 0; m < 2; ++m)
                #pragma unroll
                for (int n = 0; n < 2; ++n)
                    acc[m][n] = __builtin_amdgcn_mfma_f32_16x16x32_bf16(a[m], b[n], acc[m][n], 0, 0, 0);
        }
    }
    const int orow = (l >> 4) * 4;
    #pragma unroll
    for (int m = 0; m < 2; ++m) {
        #pragma unroll
        for (int n = 0; n < 2; ++n) {
            int col = bn + wc * 32 + n * 16 + lm;
            float bv = bias[col];
            #pragma unroll
            for (int r = 0; r < 4; ++r) {
                int row = bm + wr * 32 + m * 16 + orow + r;
                C[(size_t)row * N + col] = acc[m][n][r] + bv;
            }
        }
    }
}

// ------ split qkv + rope -> qb (unscaled), q_ext (scaled), k_ext, vT -------
__global__ __launch_bounds__(256) void split_rope_kernel(
    const float* __restrict__ qkv_raw,
    const float* __restrict__ cost, const float* __restrict__ sint,
    short* __restrict__ qb, short* __restrict__ q_ext,
    short* __restrict__ k_ext, short* __restrict__ vT)
{
    __shared__ short vt_s[64][72];
    const int h = blockIdx.y;
    const int l0 = blockIdx.x * 64;
    const int t = threadIdx.x;
    const int tok = t >> 2, dq = (t & 3) * 16;
    const int l = l0 + tok;
    const float* row = qkv_raw + (size_t)l * QKVN + h * HD;

    bf16x8 qv[2], qe[2], kv[2];
    #pragma unroll
    for (int i = 0; i < 16; i += 4) {
        int d = dq + i;
        float4 tq = *(const float4*)&row[d];
        float4 tk = *(const float4*)&row[DIMC + d];
        float4 tv = *(const float4*)&row[2 * DIMC + d];
        float2 c01 = *(const float2*)&cost[l * 32 + d / 2];
        float2 s01 = *(const float2*)&sint[l * 32 + d / 2];
        float q0 = tq.x * c01.x - tq.y * s01.x;
        float q1 = tq.x * s01.x + tq.y * c01.x;
        float q2 = tq.z * c01.y - tq.w * s01.y;
        float q3 = tq.z * s01.y + tq.w * c01.y;
        qv[i >> 3][(i & 7) + 0] = f2b(q0);
        qv[i >> 3][(i & 7) + 1] = f2b(q1);
        qv[i >> 3][(i & 7) + 2] = f2b(q2);
        qv[i >> 3][(i & 7) + 3] = f2b(q3);
        qe[i >> 3][(i & 7) + 0] = f2b(q0 * SCALE);
        qe[i >> 3][(i & 7) + 1] = f2b(q1 * SCALE);
        qe[i >> 3][(i & 7) + 2] = f2b(q2 * SCALE);
        qe[i >> 3][(i & 7) + 3] = f2b(q3 * SCALE);
        kv[i >> 3][(i & 7) + 0] = f2b(tk.x * c01.x - tk.y * s01.x);
        kv[i >> 3][(i & 7) + 1] = f2b(tk.x * s01.x + tk.y * c01.x);
        kv[i >> 3][(i & 7) + 2] = f2b(tk.z * c01.y - tk.w * s01.y);
        kv[i >> 3][(i & 7) + 3] = f2b(tk.z * s01.y + tk.w * c01.y);
        vt_s[d + 0][tok] = f2b(tv.x);
        vt_s[d + 1][tok] = f2b(tv.y);
        vt_s[d + 2][tok] = f2b(tv.z);
        vt_s[d + 3][tok] = f2b(tv.w);
    }
    size_t qbase = ((size_t)h * LTOK + l) * HD + dq;
    *(bf16x8*)&qb[qbase]     = qv[0];
    *(bf16x8*)&qb[qbase + 8] = qv[1];
    size_t ebase = ((size_t)h * LTOK + l) * EXT + dq;
    *(bf16x8*)&q_ext[ebase]     = qe[0];
    *(bf16x8*)&q_ext[ebase + 8] = qe[1];
    *(bf16x8*)&k_ext[ebase]     = kv[0];
    *(bf16x8*)&k_ext[ebase + 8] = kv[1];
    // one-hot region of k_ext: cols 64..159; 1.0 at 64+khi and 112+kwi
    for (int i = t; i < 64 * 12; i += 256) {
        int key = l0 + i / 12;
        int seg = i % 12;
        int khi = key / WG, kwi = key - khi * WG;
        const short one = f2b(1.0f);
        bf16x8 oh;
        #pragma unroll
        for (int j = 0; j < 8; ++j) {
            int col = 64 + seg * 8 + j;
            oh[j] = (col == 64 + khi || col == 112 + kwi) ? one : (short)0;
        }
        *(bf16x8*)&k_ext[((size_t)h * LTOK + key) * EXT + 64 + seg * 8] = oh;
    }
    __syncthreads();
    const int drow = t >> 2, lq = (t & 3) * 16;
    bf16x8 v0 = *(bf16x8*)&vt_s[drow][lq];
    bf16x8 v1 = *(bf16x8*)&vt_s[drow][lq + 8];
    size_t vbase = ((size_t)h * HD + drow) * LTOK + l0 + lq;
    *(bf16x8*)&vT[vbase]     = v0;
    *(bf16x8*)&vT[vbase + 8] = v1;
}

// ----------------- decomposed rel-pos bias -> q_ext cols 64..159 -----------
__global__ __launch_bounds__(256) void relbias_kernel(
    const short* __restrict__ qb,
    const float* __restrict__ rel_pos_h, const float* __restrict__ rel_pos_w,
    short* __restrict__ q_ext)
{
    __shared__ float qs2[16][68];
    __shared__ float rph_s[48][68];
    __shared__ float rpw_s[63][68];
    __shared__ short outb[16][96];
    const int nb = blockIdx.y;
    const int l0 = blockIdx.x * 16;
    const int h0 = l0 / WG, w0 = l0 % WG;
    const int t = threadIdx.x;
    {
        int flat = t * 4;
        int row = flat >> 6, col = flat & 63;
        const short* src = &qb[((size_t)nb * LTOK + l0 + row) * HD + col];
        qs2[row][col] = b2f(src[0]); qs2[row][col + 1] = b2f(src[1]);
        qs2[row][col + 2] = b2f(src[2]); qs2[row][col + 3] = b2f(src[3]);
    }
    for (int i = t; i < (48 + 63) * 16; i += 256) {
        int rr = i >> 4, c4 = (i & 15) * 4;
        if (rr < 48)
            *(float4*)&rph_s[rr][c4] = *(const float4*)&rel_pos_h[(size_t)(h0 + rr) * HD + c4];
        else
            *(float4*)&rpw_s[rr - 48][c4] = *(const float4*)&rel_pos_w[(size_t)(w0 + rr - 48) * HD + c4];
    }
    __syncthreads();
    const int ti = t >> 4, kg = t & 15;
    for (int ko = kg; ko < 96; ko += 16) {
        bool ish = ko < 48;
        int kk = ish ? ko : ko - 48;
        const float* br = ish ? &rph_s[47 - kk][0] : &rpw_s[ti + 47 - kk][0];
        float s = 0.f;
        #pragma unroll
        for (int c = 0; c < HD; c += 4) {
            float4 a = *(const float4*)&qs2[ti][c];
            float4 b = *(const float4*)&br[c];
            s += a.x * b.x + a.y * b.y + a.z * b.z + a.w * b.w;
        }
        outb[ti][ko] = f2b(s);
    }
    __syncthreads();
    if (t < 192) {
        int row = t / 12, c8 = (t % 12) * 8;
        *(bf16x8*)&q_ext[((size_t)nb * LTOK + l0 + row) * EXT + 64 + c8] =
            *(const bf16x8*)&outb[row][c8];
    }
}

// --------------------------- split-K flash attention -----------------------
// grid (18, 12, 3): block = (128 q-rows, head, key-split of 768 keys).
// 4 waves; wave w owns q-rows [w*32, w*32+32) as 2 sub-tiles of 16.
// Swapped S MFMA (A=K, B=Q) with PERMUTED K staging: lds key-slot (f,m) holds
// actual key kappa = 32*(f>>1) + 8*(m>>2) + 4*(f&1) + (m&3), so each lane's
// S output IS its PV A-fragment (keys 8g..8g+7, 32+8g..32+8g+7) -- in-lane
// exp+pack, no P LDS round-trip, no cross-lane ops, per-lane lsum.
__global__ __launch_bounds__(256, 3) void attn_kernel(
    const short* __restrict__ q_ext, const short* __restrict__ k_ext,
    const short* __restrict__ vT, float* __restrict__ o_part,
    float* __restrict__ lsum_g)
{
    __shared__ short ks[64][168];    // permuted [key-slot][ext-dim]
    __shared__ short vs[64][72];     // [d][key] (normal key order)

    const int n = blockIdx.y;
    const int qblk = blockIdx.x;
    const int sp = blockIdx.z;
    const int q0 = qblk * 128;
    const int key_base = sp * KPS;
    const int tid = threadIdx.x;
    const int w = tid >> 6, l = tid & 63;
    const int lm = l & 15, g = l >> 4;
    const int lk = g * 8;

    const short* qeh = q_ext + (size_t)n * LTOK * EXT;
    const short* keh = k_ext + (size_t)n * LTOK * EXT;
    const short* vh  = vT + (size_t)n * HD * LTOK;

    // Q_ext B-frags for 2 q-subtiles, resident in regs (rows q0+w*32+t*16+lm)
    bf16x8 qf[2][5];
    #pragma unroll
    for (int t = 0; t < 2; ++t)
        #pragma unroll
        for (int kk = 0; kk < 5; ++kk)
            qf[t][kk] = *(const bf16x8*)&qeh[(size_t)(q0 + w * 32 + t * 16 + lm) * EXT + kk * 32 + lk];

    bf16x8 kreg[5], vreg[2];
    #define ISSUE_LOADS(kt_)  do {                                              \
        const int key0_ = key_base + (kt_) * 64;                                \
        _Pragma("unroll")                                                       \
        for (int p = 0; p < 5; ++p) {                                           \
            int fl_ = tid + p * 256;                                            \
            int rho_ = fl_ / 20, c8_ = (fl_ % 20) * 8;                          \
            int f_ = rho_ >> 4, m_ = rho_ & 15;                                 \
            int kap_ = 32 * (f_ >> 1) + 8 * (m_ >> 2) + 4 * (f_ & 1) + (m_ & 3);\
            kreg[p] = *(const bf16x8*)&keh[(size_t)(key0_ + kap_) * EXT + c8_]; \
        }                                                                       \
        _Pragma("unroll")                                                       \
        for (int p = 0; p < 2; ++p) {                                           \
            int fl_ = tid + p * 256;                                            \
            int row_ = fl_ >> 3, c8_ = (fl_ & 7) * 8;                           \
            vreg[p] = *(const bf16x8*)&vh[(size_t)row_ * LTOK + key0_ + c8_];   \
        }                                                                       \
    } while (0)

    float lsum[2] = {0.f, 0.f};
    f32x4 oacc[2][4];
    const f32x4 zf = {0.f, 0.f, 0.f, 0.f};
    #pragma unroll
    for (int t = 0; t < 2; ++t)
        #pragma unroll
        for (int d = 0; d < 4; ++d) oacc[t][d] = zf;

    ISSUE_LOADS(0);

    for (int kt = 0; kt < NT; ++kt) {
        __syncthreads();   // all waves done reading LDS tile kt-1
        #pragma unroll
        for (int p = 0; p < 5; ++p) {
            int fl = tid + p * 256;
            int rho = fl / 20, c8 = (fl % 20) * 8;
            *(bf16x8*)&ks[rho][c8] = kreg[p];
        }
        #pragma unroll
        for (int p = 0; p < 2; ++p) {
            int fl = tid + p * 256;
            int row = fl >> 3, c8 = (fl & 7) * 8;
            *(bf16x8*)&vs[row][c8] = vreg[p];
        }
        if (kt + 1 < NT) { ISSUE_LOADS(kt + 1); }
        __builtin_amdgcn_sched_barrier(0);
        __syncthreads();   // LDS tile kt ready

        // S^T = K_perm . Q^T : lane (g,lm) reg r of block f holds
        // S[q=t*16+lm][key = 32*(f>>1) + 8g + 4*(f&1) + r]
        f32x4 st[2][4];
        #pragma unroll
        for (int t = 0; t < 2; ++t)
            #pragma unroll
            for (int f = 0; f < 4; ++f) st[t][f] = zf;
        #pragma unroll
        for (int f = 0; f < 4; ++f)
            #pragma unroll
            for (int kk = 0; kk < 5; ++kk) {
                bf16x8 kf = *(const bf16x8*)&ks[f * 16 + lm][kk * 32 + lk];
                st[0][f] = __builtin_amdgcn_mfma_f32_16x16x32_bf16(kf, qf[0][kk], st[0][f], 0, 0, 0);
                st[1][f] = __builtin_amdgcn_mfma_f32_16x16x32_bf16(kf, qf[1][kk], st[1][f], 0, 0, 0);
            }
        // exp + in-lane pack into PV A-frags: pf[t][kk][ (f&1)*4 + r ], kk=f>>1
        bf16x8 pf[2][2];
        #pragma unroll
        for (int t = 0; t < 2; ++t)
            #pragma unroll
            for (int f = 0; f < 4; ++f)
                #pragma unroll
                for (int r = 0; r < 4; ++r) {
                    float p = __expf(st[t][f][r]);
                    lsum[t] += p;
                    pf[t][f >> 1][(f & 1) * 4 + r] = f2b(p);
                }
        // PV: O += P @ V  (vf transient; reused across both q-subtiles)
        #pragma unroll
        for (int kk = 0; kk < 2; ++kk)
            #pragma unroll
            for (int d = 0; d < 4; ++d) {
                bf16x8 vf = *(const bf16x8*)&vs[d * 16 + lm][kk * 32 + lk];
                oacc[0][d] = __builtin_amdgcn_mfma_f32_16x16x32_bf16(pf[0][kk], vf, oacc[0][d], 0, 0, 0);
                oacc[1][d] = __builtin_amdgcn_mfma_f32_16x16x32_bf16(pf[1][kk], vf, oacc[1][d], 0, 0, 0);
            }
    }
    #undef ISSUE_LOADS

    // write unnormalized partials; O row = w*32 + t*16 + g*4 + r, col = d*16+lm
    size_t pbase = (((size_t)n * NQB2 + qblk) * NSPLIT + sp) * (128 * 64);
    #pragma unroll
    for (int t = 0; t < 2; ++t)
        #pragma unroll
        for (int d = 0; d < 4; ++d)
            #pragma unroll
            for (int r = 0; r < 4; ++r)
                o_part[pbase + (size_t)(w * 32 + t * 16 + g * 4 + r) * 64 + d * 16 + lm] = oacc[t][d][r];
    // per-row denominators: lane (g,lm) holds partial for q-row t*16+lm
    size_t lb = (((size_t)n * NQB2 + qblk) * NSPLIT + sp) * 128;
    #pragma unroll
    for (int t = 0; t < 2; ++t) {
        float s = lsum[t];
        s += __shfl_xor(s, 16);
        s += __shfl_xor(s, 32);
        if (l < 16) lsum_g[lb + w * 32 + t * 16 + l] = s;
    }
}

// --------------------------- split-K combine -------------------------------
__global__ __launch_bounds__(256) void combine_kernel(
    const float* __restrict__ o_part, const float* __restrict__ lsum_g,
    short* __restrict__ o)
{
    const int qblk = blockIdx.x, h = blockIdx.y;
    const int t = threadIdx.x;
    const int row = t >> 1, d0 = (t & 1) * 32;
    size_t sb = ((size_t)h * NQB2 + qblk) * NSPLIT;
    float ls = lsum_g[sb * 128 + row] + lsum_g[(sb + 1) * 128 + row]
             + lsum_g[(sb + 2) * 128 + row];
    float inv = 1.0f / ls;
    size_t base = sb * 8192 + (size_t)row * 64 + d0;
    float acc[32];
    #pragma unroll
    for (int c = 0; c < 32; c += 4) {
        float4 a = *(const float4*)&o_part[base + c];
        float4 b = *(const float4*)&o_part[base + 8192 + c];
        float4 gg = *(const float4*)&o_part[base + 16384 + c];
        acc[c + 0] = (a.x + b.x + gg.x) * inv;
        acc[c + 1] = (a.y + b.y + gg.y) * inv;
        acc[c + 2] = (a.z + b.z + gg.z) * inv;
        acc[c + 3] = (a.w + b.w + gg.w) * inv;
    }
    size_t ob = ((size_t)(qblk * 128 + row)) * DIMC + h * 64 + d0;
    #pragma unroll
    for (int v = 0; v < 4; ++v) {
        bf16x8 ov;
        #pragma unroll
        for (int j = 0; j < 8; ++j) ov[j] = f2b(acc[v * 8 + j]);
        *(bf16x8*)&o[ob + v * 8] = ov;
    }
}

// ---------------------------------------------------------------------------
extern "C" void kernel_launch(void* const* d_in, const int* in_sizes, int n_in,
                              void* d_out, int out_size, void* d_ws, size_t ws_size,
                              hipStream_t stream) {
    (void)in_sizes; (void)n_in; (void)out_size; (void)ws_size;
    const float* x         = (const float*)d_in[0];
    const float* w_qkv     = (const float*)d_in[1];
    const float* b_qkv     = (const float*)d_in[2];
    const float* w_proj    = (const float*)d_in[3];
    const float* b_proj    = (const float*)d_in[4];
    const float* rel_pos_h = (const float*)d_in[5];
    const float* rel_pos_w = (const float*)d_in[6];
    float* out = (float*)d_out;

    float* qkv_raw = (float*)d_ws;                         // 5.31M f32 (dead after split_rope)
    float* o_part  = qkv_raw;                              // alias: 12*18*3*8192 f32 == same size
    float* cost    = qkv_raw + (size_t)LTOK * QKVN;
    float* sint    = cost + (size_t)LTOK * 32;
    float* lsum_g  = sint + (size_t)LTOK * 32;             // 12*18*3*128 f32
    short* xb      = (short*)(lsum_g + (size_t)NH * NQB2 * NSPLIT * 128);
    short* wqkvT   = xb + (size_t)LTOK * DIMC;
    short* wprojT  = wqkvT + (size_t)QKVN * DIMC;
    short* qb      = wprojT + (size_t)DIMC * DIMC;         // unscaled rotated q
    short* q_ext   = qb + (size_t)NH * LTOK * HD;          // [h][l][160]
    short* k_ext   = q_ext + (size_t)NH * LTOK * EXT;      // [h][key][160]
    short* vTb     = k_ext + (size_t)NH * LTOK * EXT;      // [h][d][L]
    short* ob      = vTb + (size_t)NH * LTOK * HD;         // L*768

    rope_table_kernel<<<(LTOK * 32 + 255) / 256, 256, 0, stream>>>(cost, sint);

    cast_bf16_kernel<<<(LTOK * DIMC / 8 + 255) / 256, 256, 0, stream>>>(
        x, xb, LTOK * DIMC / 8);
    transpose_cast_kernel<<<dim3(QKVN / 32, DIMC / 32), 256, 0, stream>>>(
        w_qkv, wqkvT, DIMC, QKVN);
    transpose_cast_kernel<<<dim3(DIMC / 32, DIMC / 32), 256, 0, stream>>>(
        w_proj, wprojT, DIMC, DIMC);

    gemm_bf16_kernel<<<dim3(QKVN / 128, LTOK / 128), 256, 0, stream>>>(
        xb, wqkvT, b_qkv, qkv_raw, LTOK, QKVN, DIMC);

    split_rope_kernel<<<dim3(LTOK / 64, NH), 256, 0, stream>>>(
        qkv_raw, cost, sint, qb, q_ext, k_ext, vTb);

    relbias_kernel<<<dim3(LTOK / 16, NH), 256, 0, stream>>>(
        qb, rel_pos_h, rel_pos_w, q_ext);

    attn_kernel<<<dim3(NQB2, NH, NSPLIT), 256, 0, stream>>>(
        q_ext, k_ext, vTb, o_part, lsum_g);

    combine_kernel<<<dim3(NQB2, NH), 256, 0, stream>>>(o_part, lsum_g, ob);

    gemm64_bf16_kernel<<<dim3(DIMC / 64, LTOK / 64), 256, 0, stream>>>(
        ob, wprojT, b_proj, out, LTOK, DIMC, DIMC);
}